// Round 3
// baseline (620.466 us; speedup 1.0000x reference)
//
#include <hip/hip_runtime.h>

typedef unsigned short u16;
typedef unsigned int u32;
typedef short short8 __attribute__((ext_vector_type(8)));
typedef float float4v __attribute__((ext_vector_type(4)));

#define L_SEQ 1024
#define NB 4
#define NH 16
#define DK 128
#define DV 128
#define HID 2048
#define NQKVZ 8192
#define CONV_DIM 6144
#define GDN_SCALE 0.08838834764831845f  // 128^-0.5

static __device__ __forceinline__ float bf2f(u16 u) {
    union { u32 i; float f; } x; x.i = ((u32)u) << 16; return x.f;
}
static __device__ __forceinline__ u16 f2bf(float f) {
    union { float f; u32 u; } x; x.f = f;
    u32 r = x.u + 0x7FFF + ((x.u >> 16) & 1);
    return (u16)(r >> 16);
}

union FragU { short8 v; uint4 u; };

// async global->LDS, 16B per lane (lane-contiguous LDS dest required).
#define GLOAD_LDS16(g, l)                                        \
    __builtin_amdgcn_global_load_lds(                            \
        (const __attribute__((address_space(1))) void*)(g),      \
        (__attribute__((address_space(3))) void*)(l), 16, 0, 0)

// ---------------- fp32 -> bf16 elementwise convert ---------------------------
__global__ __launch_bounds__(256) void f32_to_bf16(
    const float* __restrict__ in, u16* __restrict__ out) {
    long i = ((long)blockIdx.x * 256 + threadIdx.x) * 8;
    float4 a = *(const float4*)(in + i);
    float4 b = *(const float4*)(in + i + 4);
    u16 tmp[8];
    tmp[0] = f2bf(a.x); tmp[1] = f2bf(a.y); tmp[2] = f2bf(a.z); tmp[3] = f2bf(a.w);
    tmp[4] = f2bf(b.x); tmp[5] = f2bf(b.y); tmp[6] = f2bf(b.z); tmp[7] = f2bf(b.w);
    *(uint4*)(out + i) = *(const uint4*)tmp;
}

// ---------------- transpose fp32 (RxC) -> bf16 (CxR) -------------------------
__global__ __launch_bounds__(256) void transpose_f32_bf16(
    const float* __restrict__ in, u16* __restrict__ out, int R, int C) {
    __shared__ float tile[32][33];
    int bx = blockIdx.x, by = blockIdx.y;
    int c = threadIdx.x & 31;
    int r0 = threadIdx.x >> 5;
#pragma unroll
    for (int i = 0; i < 4; i++) {
        int r = r0 + i * 8;
        tile[r][c] = in[(long)(by * 32 + r) * C + bx * 32 + c];
    }
    __syncthreads();
#pragma unroll
    for (int i = 0; i < 4; i++) {
        int r = r0 + i * 8;
        out[(long)(bx * 32 + r) * R + by * 32 + c] = f2bf(tile[c][r]);
    }
}

// ---------------- GEMM (m97 structure): C = A * BT^T, bf16 in, OutT out ------
#define BM 128
#define BN 128
#define BKK 32

static __device__ __forceinline__ void store_out(u16* p, float v)  { *p = f2bf(v); }
static __device__ __forceinline__ void store_out(float* p, float v){ *p = v; }

template <typename OutT>
__global__ __launch_bounds__(256) void gemm_abT(
    const u16* __restrict__ A, const u16* __restrict__ BT,
    OutT* __restrict__ C, int M, int N, int K) {
    __shared__ u16 As[BM * BKK];
    __shared__ u16 Bs[BN * BKK];
    int t = threadIdx.x;
    int lane = t & 63;
    int w = t >> 6;
    int wm = (w & 1) * 64;
    int wn = (w >> 1) * 64;
    int l15 = lane & 15;
    int quad = lane >> 4;
    long blockM = (long)blockIdx.y * BM;
    long blockN = (long)blockIdx.x * BN;

    float4v acc[4][4];
#pragma unroll
    for (int i = 0; i < 4; i++)
#pragma unroll
        for (int j = 0; j < 4; j++) acc[i][j] = (float4v){0.f, 0.f, 0.f, 0.f};

    const u16* Ab = A + blockM * K;
    const u16* Bb = BT + blockN * K;

    const int r0 = t >> 2,         c0 = (t & 3) * 8;
    const int r1 = (t + 256) >> 2, c1 = ((t + 256) & 3) * 8;
    u16* As0 = As + t * 8;         u16* As1 = As + (t + 256) * 8;
    u16* Bs0 = Bs + t * 8;         u16* Bs1 = Bs + (t + 256) * 8;
    const u16* Ag0 = Ab + (long)r0 * K + c0;
    const u16* Ag1 = Ab + (long)r1 * K + c1;
    const u16* Bg0 = Bb + (long)r0 * K + c0;
    const u16* Bg1 = Bb + (long)r1 * K + c1;

    for (int k0 = 0; k0 < K; k0 += BKK) {
        __syncthreads();
        GLOAD_LDS16(Ag0 + k0, As0);
        GLOAD_LDS16(Ag1 + k0, As1);
        GLOAD_LDS16(Bg0 + k0, Bs0);
        GLOAD_LDS16(Bg1 + k0, Bs1);
        __syncthreads();

        FragU fa[4], fb[4];
#pragma unroll
        for (int i = 0; i < 4; i++) {
            fa[i].u = *(const uint4*)(As + (wm + i * 16 + l15) * BKK + quad * 8);
            fb[i].u = *(const uint4*)(Bs + (wn + i * 16 + l15) * BKK + quad * 8);
        }
#pragma unroll
        for (int i = 0; i < 4; i++)
#pragma unroll
            for (int j = 0; j < 4; j++)
                acc[i][j] = __builtin_amdgcn_mfma_f32_16x16x32_bf16(
                    fa[i].v, fb[j].v, acc[i][j], 0, 0, 0);
    }

#pragma unroll
    for (int i = 0; i < 4; i++) {
        long mrow = blockM + wm + i * 16 + quad * 4;
#pragma unroll
        for (int j = 0; j < 4; j++) {
            long col = blockN + wn + j * 16 + l15;
#pragma unroll
            for (int r = 0; r < 4; r++) {
                store_out(&C[(mrow + r) * N + col], acc[i][j][r]);
            }
        }
    }
}

// ---------------- GEMM1: 256x256 tile, BK=64, 4-phase, deep counted vmcnt ----
// 8 waves (2M x 4N), 512 threads. LDS = 2 dbuf x (A 256x64 + B 256x64) = 128KB.
// Stage map (cover-depth arithmetic): ph1->B01(g+1), ph2->B23(g+1),
// ph3->A02(g+2) into CURRENT buf (region dead since ph1, ph2-barrier
// guarantees), ph4->A13(g+1). Waits: vmcnt(4)+barrier before ph3 reads
// (A13(g), 3-phase cover), vmcnt(4)+barrier at group end (B(g+1), 2-3-phase
// cover). 4 barriers/group, max 4 loads drained per wait.
// Swizzle: 16B chunk ^= row&7, pre-swizzled global source + swizzled ds_read.
#define G1_LDSU 32768  // u16 per dbuf (64 KB)

__global__ __launch_bounds__(512, 2) void gemm1_8ph(
    const u16* __restrict__ A, const u16* __restrict__ BT,
    u16* __restrict__ C) {
    const int K = HID, N = NQKVZ;
    __shared__ __align__(16) u16 lds[2 * G1_LDSU];  // 128 KB

    int t = threadIdx.x;
    int lane = t & 63, w = t >> 6, l15 = lane & 15, quad = lane >> 4;
    int wm = w & 1, wn = w >> 1;

    // XCD patch swizzle: 512 wgs, XCD = orig&7 owns patch of 8x8 tiles
    int orig = blockIdx.x;
    int wg = (orig & 7) * 64 + (orig >> 3);
    int p = wg >> 6, q = wg & 63;
    long blockM = (long)((p >> 2) * 8 + (q >> 3)) * 256;  // 0..15
    long blockN = (long)((p & 3) * 8 + (q & 7)) * 256;    // 0..31

    // staging: thread t covers (row-in-quarter = t>>3, chunk = t&7);
    // global chunk pre-swizzled so LDS dest stays lane-linear.
    int srow = t >> 3;
    int scol = ((t & 7) ^ (srow & 7)) * 8;
    const u16* Ast = A + (blockM + srow) * (long)K + scol;
    const u16* Bst = BT + (blockN + srow) * (long)K + scol;

    // A quarter q (64 rows) at dbuf*G1_LDSU + q*4096; B at +16384 + q*4096.
#define STA(db, qq, T) GLOAD_LDS16(Ast + (long)(qq) * 64 * K + (T) * 64,      \
                                   lds + (db) * G1_LDSU + (qq) * 4096 + t * 8)
#define STB(db, qq, T) GLOAD_LDS16(Bst + (long)(qq) * 64 * K + (T) * 64,      \
                                   lds + (db) * G1_LDSU + 16384 + (qq) * 4096 + t * 8)

    // fragment read offsets (u16 units): row*64 + ((kc)^(row&7))*8
    const int rowA0 = (wm * 128 + l15) * 64;
    const int rowB0 = 16384 + (wn * 64 + l15) * 64;
    const int cs0 = ((quad) ^ (l15 & 7)) * 8;        // kk=0 chunk
    const int cs1 = ((4 + quad) ^ (l15 & 7)) * 8;    // kk=1 chunk

    float4v acc[8][4];
#pragma unroll
    for (int mi = 0; mi < 8; mi++)
#pragma unroll
        for (int nj = 0; nj < 4; nj++) acc[mi][nj] = (float4v){0.f, 0.f, 0.f, 0.f};

    // prologue (emulates steady-state issue order):
    // A02(T0), B01(T0), B23(T0), A02(T1), A13(T0) — 10 loads, drain to 4.
    STA(0, 0, 0); STA(0, 2, 0);
    STB(0, 0, 0); STB(0, 1, 0);
    STB(0, 2, 0); STB(0, 3, 0);
    STA(1, 0, 1); STA(1, 2, 1);
    STA(0, 1, 0); STA(0, 3, 0);
    asm volatile("s_waitcnt vmcnt(4)" ::: "memory");
    __builtin_amdgcn_s_barrier();

    FragU bA[4][2], bB0[2][2], bB1[2][2];

    for (int g = 0; g < 32; ++g) {
        const int c = g & 1, db = c ^ 1;
        const u16* sb = lds + c * G1_LDSU;

        // ---- ph1 (mh0,nh0): reads A0-3 + B0-1; stage B01(g+1) -> db ----
#pragma unroll
        for (int i = 0; i < 4; i++) {
            bA[i][0].u = *(const uint4*)(sb + rowA0 + i * 1024 + cs0);
            bA[i][1].u = *(const uint4*)(sb + rowA0 + i * 1024 + cs1);
        }
#pragma unroll
        for (int j = 0; j < 2; j++) {
            bB0[j][0].u = *(const uint4*)(sb + rowB0 + j * 1024 + cs0);
            bB0[j][1].u = *(const uint4*)(sb + rowB0 + j * 1024 + cs1);
        }
        if (g < 31) { STB(db, 0, g + 1); STB(db, 1, g + 1); }
        asm volatile("s_waitcnt lgkmcnt(8)" ::: "memory");
        __builtin_amdgcn_s_barrier();
        __builtin_amdgcn_s_setprio(1);
#pragma unroll
        for (int i = 0; i < 4; i++)
#pragma unroll
            for (int j = 0; j < 2; j++) {
                acc[i][j] = __builtin_amdgcn_mfma_f32_16x16x32_bf16(
                    bA[i][0].v, bB0[j][0].v, acc[i][j], 0, 0, 0);
                acc[i][j] = __builtin_amdgcn_mfma_f32_16x16x32_bf16(
                    bA[i][1].v, bB0[j][1].v, acc[i][j], 0, 0, 0);
            }
        __builtin_amdgcn_s_setprio(0);

        // ---- ph2 (mh0,nh1): reads B2-3; stage B23(g+1) -> db ----
#pragma unroll
        for (int j = 0; j < 2; j++) {
            bB1[j][0].u = *(const uint4*)(sb + rowB0 + (2 + j) * 1024 + cs0);
            bB1[j][1].u = *(const uint4*)(sb + rowB0 + (2 + j) * 1024 + cs1);
        }
        if (g < 31) { STB(db, 2, g + 1); STB(db, 3, g + 1); }
        __builtin_amdgcn_s_barrier();
        __builtin_amdgcn_s_setprio(1);
#pragma unroll
        for (int i = 0; i < 4; i++)
#pragma unroll
            for (int j = 0; j < 2; j++) {
                acc[i][2 + j] = __builtin_amdgcn_mfma_f32_16x16x32_bf16(
                    bA[i][0].v, bB1[j][0].v, acc[i][2 + j], 0, 0, 0);
                acc[i][2 + j] = __builtin_amdgcn_mfma_f32_16x16x32_bf16(
                    bA[i][1].v, bB1[j][1].v, acc[i][2 + j], 0, 0, 0);
            }
        __builtin_amdgcn_s_setprio(0);

        // ---- ph3 (mh1,nh0): W2 wait (A13(g) resident), reads A4-7;
        //      stage A02(g+2) -> CURRENT buf (dead since ph1) ----
        if (g < 31) { asm volatile("s_waitcnt vmcnt(4)" ::: "memory"); }
        else        { asm volatile("s_waitcnt vmcnt(0)" ::: "memory"); }
        __builtin_amdgcn_s_barrier();
        if (g < 30) { STA(c, 0, g + 2); STA(c, 2, g + 2); }
#pragma unroll
        for (int i = 0; i < 4; i++) {
            bA[i][0].u = *(const uint4*)(sb + rowA0 + (4 + i) * 1024 + cs0);
            bA[i][1].u = *(const uint4*)(sb + rowA0 + (4 + i) * 1024 + cs1);
        }
        __builtin_amdgcn_s_setprio(1);
#pragma unroll
        for (int i = 0; i < 4; i++)
#pragma unroll
            for (int j = 0; j < 2; j++) {
                acc[4 + i][j] = __builtin_amdgcn_mfma_f32_16x16x32_bf16(
                    bA[i][0].v, bB0[j][0].v, acc[4 + i][j], 0, 0, 0);
                acc[4 + i][j] = __builtin_amdgcn_mfma_f32_16x16x32_bf16(
                    bA[i][1].v, bB0[j][1].v, acc[4 + i][j], 0, 0, 0);
            }
        __builtin_amdgcn_s_setprio(0);

        // ---- ph4 (mh1,nh1): stage A13(g+1) -> db; MFMA (no barrier) ----
        if (g < 31) { STA(db, 1, g + 1); STA(db, 3, g + 1); }
        __builtin_amdgcn_s_setprio(1);
#pragma unroll
        for (int i = 0; i < 4; i++)
#pragma unroll
            for (int j = 0; j < 2; j++) {
                acc[4 + i][2 + j] = __builtin_amdgcn_mfma_f32_16x16x32_bf16(
                    bA[i][0].v, bB1[j][0].v, acc[4 + i][2 + j], 0, 0, 0);
                acc[4 + i][2 + j] = __builtin_amdgcn_mfma_f32_16x16x32_bf16(
                    bA[i][1].v, bB1[j][1].v, acc[4 + i][2 + j], 0, 0, 0);
            }
        __builtin_amdgcn_s_setprio(0);

        // ---- W1: tile g+1's B resident (2-3 phase cover) ----
        if (g < 30)       { asm volatile("s_waitcnt vmcnt(4)" ::: "memory"); }
        else if (g == 30) { asm volatile("s_waitcnt vmcnt(2)" ::: "memory"); }
        if (g < 31) __builtin_amdgcn_s_barrier();
    }

    // epilogue: C[row][col]
#pragma unroll
    for (int mi = 0; mi < 8; mi++) {
        long row0 = blockM + wm * 128 + mi * 16 + quad * 4;
#pragma unroll
        for (int nj = 0; nj < 4; nj++) {
            long col = blockN + wn * 64 + nj * 16 + l15;
#pragma unroll
            for (int r = 0; r < 4; r++)
                C[(row0 + r) * N + col] = f2bf(acc[mi][nj][r]);
        }
    }
#undef STA
#undef STB
}

// ---------------- GEMM2: 256x128 tile, BK=64, 2-phase, counted vmcnt ---------
// 256 wgs (1/CU), 8 waves (2M x 4N -> per-wave 128x32), 96 KB LDS.
// Stage map: ph1 -> Aq1,Aq3(g+1); ph2(post-barrier) -> Aq0,Aq2,Bh0,Bh1(g+2)
// into CURRENT buf (A-low/B dead since ph1). Waits: vmcnt(6)+barrier before
// ph2 reads (A13(g), 3-phase cover); vmcnt(6)+barrier at group end (A-low+B
// of g+1, 2-phase cover). Output fp32.
#define G2_LDSU 24576  // u16 per dbuf (48 KB)

__global__ __launch_bounds__(512) void gemm2_2ph(
    const u16* __restrict__ A, const u16* __restrict__ BT,
    float* __restrict__ C) {
    const int K = HID, N = 2048;
    __shared__ __align__(16) u16 lds[2 * G2_LDSU];  // 96 KB

    int t = threadIdx.x;
    int lane = t & 63, w = t >> 6, l15 = lane & 15, quad = lane >> 4;
    int wm = w & 1, wn = w >> 1;

    // XCD swizzle: 256 wgs; XCD x owns an 8Mx4N tile patch.
    int orig = blockIdx.x;
    int x = orig & 7, q = orig >> 3;           // q in 0..31
    long blockM = (long)((x >> 2) * 8 + (q >> 2)) * 256;   // 0..15
    long blockN = (long)((x & 3) * 4 + (q & 3)) * 128;     // 0..15

    int srow = t >> 3;
    int scol = ((t & 7) ^ (srow & 7)) * 8;
    const u16* Ast = A + (blockM + srow) * (long)K + scol;
    const u16* Bst = BT + (blockN + srow) * (long)K + scol;

#define STA2(db, qq, T) GLOAD_LDS16(Ast + (long)(qq) * 64 * K + (T) * 64,     \
                                    lds + (db) * G2_LDSU + (qq) * 4096 + t * 8)
#define STB2(db, hh, T) GLOAD_LDS16(Bst + (long)(hh) * 64 * K + (T) * 64,     \
                                    lds + (db) * G2_LDSU + 16384 + (hh) * 4096 + t * 8)

    const int cs0 = ((quad) ^ (l15 & 7)) * 8;
    const int cs1 = ((4 + quad) ^ (l15 & 7)) * 8;
    // A row r = wm*128 + mi*16 + l15 -> quarter (wm*2 + (mi>>2)), local row
    // (mi&3)*16+l15. B row rb = wn*32 + nj*16 + l15 -> half (wn>>1), local
    // (wn&1)*32 + nj*16 + l15.
    int offA[8], offB[2];
#pragma unroll
    for (int mi = 0; mi < 8; mi++)
        offA[mi] = (wm * 2 + (mi >> 2)) * 4096 + (((mi & 3) * 16 + l15)) * 64;
#pragma unroll
    for (int nj = 0; nj < 2; nj++)
        offB[nj] = 16384 + (wn >> 1) * 4096 + ((wn & 1) * 32 + nj * 16 + l15) * 64;

    float4v acc[8][2];
#pragma unroll
    for (int mi = 0; mi < 8; mi++)
#pragma unroll
        for (int nj = 0; nj < 2; nj++) acc[mi][nj] = (float4v){0.f, 0.f, 0.f, 0.f};

    // prologue: T0{A02,B}, T0{A13}, T1{A02,B} — 10 loads, drain to 6.
    STA2(0, 0, 0); STA2(0, 2, 0); STB2(0, 0, 0); STB2(0, 1, 0);
    STA2(0, 1, 0); STA2(0, 3, 0);
    STA2(1, 0, 1); STA2(1, 2, 1); STB2(1, 0, 1); STB2(1, 1, 1);
    asm volatile("s_waitcnt vmcnt(6)" ::: "memory");
    __builtin_amdgcn_s_barrier();

    FragU fA[4][2], fB[2][2];

    for (int g = 0; g < 32; ++g) {
        const int c = g & 1, db = c ^ 1;
        const u16* sb = lds + c * G2_LDSU;

        // ---- ph1 (mh0): reads A0-3 (8) + B (4); stage A13(g+1) -> db ----
#pragma unroll
        for (int i = 0; i < 4; i++) {
            fA[i][0].u = *(const uint4*)(sb + offA[i] + cs0);
            fA[i][1].u = *(const uint4*)(sb + offA[i] + cs1);
        }
#pragma unroll
        for (int j = 0; j < 2; j++) {
            fB[j][0].u = *(const uint4*)(sb + offB[j] + cs0);
            fB[j][1].u = *(const uint4*)(sb + offB[j] + cs1);
        }
        if (g < 31) { STA2(db, 1, g + 1); STA2(db, 3, g + 1); }
        asm volatile("s_waitcnt lgkmcnt(8)" ::: "memory");
        __builtin_amdgcn_s_barrier();
        __builtin_amdgcn_s_setprio(1);
#pragma unroll
        for (int i = 0; i < 4; i++)
#pragma unroll
            for (int j = 0; j < 2; j++) {
                acc[i][j] = __builtin_amdgcn_mfma_f32_16x16x32_bf16(
                    fA[i][0].v, fB[j][0].v, acc[i][j], 0, 0, 0);
                acc[i][j] = __builtin_amdgcn_mfma_f32_16x16x32_bf16(
                    fA[i][1].v, fB[j][1].v, acc[i][j], 0, 0, 0);
            }
        __builtin_amdgcn_s_setprio(0);

        // ---- ph2 (mh1): W2 wait; reads A4-7; stage A02+B(g+2) -> cur ----
        if (g < 31) { asm volatile("s_waitcnt vmcnt(6)" ::: "memory"); }
        else        { asm volatile("s_waitcnt vmcnt(0)" ::: "memory"); }
        __builtin_amdgcn_s_barrier();
        if (g < 30) { STA2(c, 0, g + 2); STA2(c, 2, g + 2);
                      STB2(c, 0, g + 2); STB2(c, 1, g + 2); }
#pragma unroll
        for (int i = 0; i < 4; i++) {
            fA[i][0].u = *(const uint4*)(sb + offA[4 + i] + cs0);
            fA[i][1].u = *(const uint4*)(sb + offA[4 + i] + cs1);
        }
        __builtin_amdgcn_s_setprio(1);
#pragma unroll
        for (int i = 0; i < 4; i++)
#pragma unroll
            for (int j = 0; j < 2; j++) {
                acc[4 + i][j] = __builtin_amdgcn_mfma_f32_16x16x32_bf16(
                    fA[i][0].v, fB[j][0].v, acc[4 + i][j], 0, 0, 0);
                acc[4 + i][j] = __builtin_amdgcn_mfma_f32_16x16x32_bf16(
                    fA[i][1].v, fB[j][1].v, acc[4 + i][j], 0, 0, 0);
            }
        __builtin_amdgcn_s_setprio(0);

        // ---- W1: tile g+1's A-low + B resident ----
        if (g < 30)       { asm volatile("s_waitcnt vmcnt(6)" ::: "memory"); }
        else if (g == 30) { asm volatile("s_waitcnt vmcnt(2)" ::: "memory"); }
        if (g < 31) __builtin_amdgcn_s_barrier();
    }

    // epilogue: fp32 C
#pragma unroll
    for (int mi = 0; mi < 8; mi++) {
        long row0 = blockM + wm * 128 + mi * 16 + quad * 4;
#pragma unroll
        for (int nj = 0; nj < 2; nj++) {
            long col = blockN + wn * 32 + nj * 16 + l15;
#pragma unroll
            for (int r = 0; r < 4; r++)
                C[(row0 + r) * N + col] = acc[mi][nj][r];
        }
    }
#undef STA2
#undef STB2
}

// ---------------- ba as MFMA GEMM + fused epilogue ---------------------------
// 64 blocks x 256 thr. M=64/block, N=32, K=2048. A=hsb, BT=WbaTb (32x2048).
__global__ __launch_bounds__(256) void ba_gemm(
    const u16* __restrict__ hsb, const u16* __restrict__ WbaTb,
    const float* __restrict__ A_log, const float* __restrict__ dtb,
    float* __restrict__ gout, float* __restrict__ bout) {
    __shared__ u16 As[64 * 32];
    __shared__ u16 Bs[32 * 32];
    int t = threadIdx.x;
    int lane = t & 63, w = t >> 6, l15 = lane & 15, quad = lane >> 4;
    long blockM = (long)blockIdx.x * 64;

    float4v acc[2];
    acc[0] = (float4v){0.f, 0.f, 0.f, 0.f};
    acc[1] = (float4v){0.f, 0.f, 0.f, 0.f};

    const u16* Ag = hsb + (blockM + (t >> 2)) * (long)HID + (t & 3) * 8;
    const u16* Bg = WbaTb + (long)(t >> 2) * HID + (t & 3) * 8;  // valid t<128

    for (int k0 = 0; k0 < HID; k0 += 32) {
        __syncthreads();
        GLOAD_LDS16(Ag + k0, As + t * 8);
        if (t < 128) GLOAD_LDS16(Bg + k0, Bs + t * 8);
        __syncthreads();
        FragU fa, fb[2];
        fa.u = *(const uint4*)(As + (w * 16 + l15) * 32 + quad * 8);
#pragma unroll
        for (int j = 0; j < 2; j++)
            fb[j].u = *(const uint4*)(Bs + (j * 16 + l15) * 32 + quad * 8);
#pragma unroll
        for (int j = 0; j < 2; j++)
            acc[j] = __builtin_amdgcn_mfma_f32_16x16x32_bf16(
                fa.v, fb[j].v, acc[j], 0, 0, 0);
    }

#pragma unroll
    for (int j = 0; j < 2; j++) {
        int n = j * 16 + l15;
#pragma unroll
        for (int r = 0; r < 4; r++) {
            long m = blockM + w * 16 + quad * 4 + r;
            int b = (int)(m >> 10), l = (int)(m & 1023);
            float v = acc[j][r];
            if (n < 16) {
                bout[((long)(b * NH + n)) * L_SEQ + l] = 1.f / (1.f + expf(-v));
            } else {
                int h = n - 16;
                float x = v + dtb[h];
                float sp = (x > 20.f) ? x : log1pf(expf(x));
                gout[((long)(b * NH + h)) * L_SEQ + l] = -expf(A_log[h]) * sp;
            }
        }
    }
}

// ---------------- conv(KS=4) + l2norm(q,k) + split v -> bf16 -----------------
__global__ __launch_bounds__(256) void conv_qkv(
    const u16* __restrict__ qkvz, const float* __restrict__ conv_w,
    const float* __restrict__ conv_b,
    u16* __restrict__ qs, u16* __restrict__ ks, u16* __restrict__ vs) {
    int bl = blockIdx.x;  // b*L + l
    int b = bl >> 10, l = bl & 1023;
    int t = threadIdx.x;
    __shared__ float xb[CONV_DIM];
    __shared__ float red[32][9];
    __shared__ float rbuf[32];

    for (int c = t; c < CONV_DIM; c += 256) {
        float acc = conv_b[c];
        float w0 = conv_w[c * 4 + 0];
        float w1 = conv_w[c * 4 + 1];
        float w2 = conv_w[c * 4 + 2];
        float w3 = conv_w[c * 4 + 3];
        long rowbase = (long)(b * L_SEQ) * NQKVZ + c;
        if (l - 3 >= 0) acc += bf2f(qkvz[rowbase + (long)(l - 3) * NQKVZ]) * w0;
        if (l - 2 >= 0) acc += bf2f(qkvz[rowbase + (long)(l - 2) * NQKVZ]) * w1;
        if (l - 1 >= 0) acc += bf2f(qkvz[rowbase + (long)(l - 1) * NQKVZ]) * w2;
        acc += bf2f(qkvz[rowbase + (long)l * NQKVZ]) * w3;
        xb[c] = acc;
    }
    __syncthreads();
    {
        int grp = t >> 3;
        int j8 = t & 7;
        float s = 0.f;
#pragma unroll
        for (int i = 0; i < 16; i++) {
            float xv = xb[grp * 128 + j8 * 16 + i];
            s += xv * xv;
        }
        red[grp][j8] = s;
    }
    __syncthreads();
    if (t < 32) {
        float s = 0.f;
#pragma unroll
        for (int i = 0; i < 8; i++) s += red[t][i];
        rbuf[t] = rsqrtf(s + 1e-6f);
    }
    __syncthreads();
    for (int c = t; c < CONV_DIM; c += 256) {
        float xv = xb[c];
        if (c < 2048) {
            int h = c >> 7, d = c & 127;
            qs[(((long)(b * NH + h)) * L_SEQ + l) * DK + d] = f2bf(xv * rbuf[h]);
        } else if (c < 4096) {
            int c2 = c - 2048;
            int h = c2 >> 7, d = c2 & 127;
            ks[(((long)(b * NH + h)) * L_SEQ + l) * DK + d] = f2bf(xv * rbuf[16 + h]);
        } else {
            int c2 = c - 4096;
            int h = c2 >> 7, d = c2 & 127;
            vs[(((long)(b * NH + h)) * L_SEQ + l) * DV + d] = f2bf(xv);
        }
    }
}

// ---------------- gdn_prep v2: per-chunk T, P, wb, ql, kd, gam ---------------
// 1024 blocks = (bh=64) x (chunk=16); 256 threads (4 waves).
// Prefix scan via shuffle; fwd-subst = 2 parallel 32x32 (waves 0,1) +
// all-thread VALU combine T21 = -T22*A21*T11.
__global__ __launch_bounds__(256) void gdn_prep(
    const u16* __restrict__ ks_g, const u16* __restrict__ qs_g,
    const float* __restrict__ g_g, const float* __restrict__ b_g,
    u16* __restrict__ Tbuf, u16* __restrict__ Pbuf,
    u16* __restrict__ wbq, u16* __restrict__ qlq, u16* __restrict__ kdq,
    float* __restrict__ gam_g) {
    int cid = blockIdx.x;
    int bh = cid >> 4;
    int ch = cid & 15;
    long rowbase = (long)bh * L_SEQ + ch * 64;
    int t = threadIdx.x;
    int lane = t & 63, w = t >> 6, l15 = lane & 15, quad = lane >> 4;

    __shared__ u16 Kl[64 * 136];
    __shared__ u16 Ql[64 * 136];
    __shared__ float Am[64 * 66];
    __shared__ float Tm[64 * 66];
    __shared__ float Tt[32 * 33];
    __shared__ float Gs[64], lamL[64], betaL[64], dlL[64];

    {   // stage K,Q rows bf16 -> padded LDS; stage g, beta
        int row = t >> 2, seg = (t & 3) * 32;
        const u16* ksrc = ks_g + (rowbase + row) * DK + seg;
        const u16* qsrc = qs_g + (rowbase + row) * DK + seg;
        *(uint4*)&Kl[row * 136 + seg]      = *(const uint4*)ksrc;
        *(uint4*)&Kl[row * 136 + seg + 8]  = *(const uint4*)(ksrc + 8);
        *(uint4*)&Kl[row * 136 + seg + 16] = *(const uint4*)(ksrc + 16);
        *(uint4*)&Kl[row * 136 + seg + 24] = *(const uint4*)(ksrc + 24);
        *(uint4*)&Ql[row * 136 + seg]      = *(const uint4*)qsrc;
        *(uint4*)&Ql[row * 136 + seg + 8]  = *(const uint4*)(qsrc + 8);
        *(uint4*)&Ql[row * 136 + seg + 16] = *(const uint4*)(qsrc + 16);
        *(uint4*)&Ql[row * 136 + seg + 24] = *(const uint4*)(qsrc + 24);
        if (t < 64) Gs[t] = g_g[rowbase + t];
        else if (t < 128) betaL[t - 64] = b_g[rowbase + t - 64];
    }
    __syncthreads();
    if (t < 64) {   // inclusive prefix scan (Kogge-Stone, wave 0)
        float gv = Gs[t];
#pragma unroll
        for (int off = 1; off < 64; off <<= 1) {
            float n = __shfl_up(gv, off);
            if (lane >= off) gv += n;
        }
        Gs[t] = gv;
    }
    __syncthreads();
    if (t < 64) {
        float G63 = Gs[63];
        float lm = expf(Gs[t]);
        lamL[t] = lm;
        dlL[t] = expf(G63 - Gs[t]);
        if (t == 0) gam_g[cid] = expf(G63);
    }
    // MFMA: KK^T and QK^T (wave w = row-stripe w*16)
    float4v accKK[4], accQK[4];
#pragma unroll
    for (int tj = 0; tj < 4; tj++) {
        accKK[tj] = (float4v){0.f, 0.f, 0.f, 0.f};
        accQK[tj] = (float4v){0.f, 0.f, 0.f, 0.f};
    }
#pragma unroll
    for (int k0 = 0; k0 < 128; k0 += 32) {
        FragU ka, qa;
        ka.u = *(const uint4*)&Kl[(w * 16 + l15) * 136 + k0 + quad * 8];
        qa.u = *(const uint4*)&Ql[(w * 16 + l15) * 136 + k0 + quad * 8];
#pragma unroll
        for (int tj = 0; tj < 4; tj++) {
            FragU kb;
            kb.u = *(const uint4*)&Kl[(tj * 16 + l15) * 136 + k0 + quad * 8];
            accKK[tj] = __builtin_amdgcn_mfma_f32_16x16x32_bf16(ka.v, kb.v, accKK[tj], 0, 0, 0);
            accQK[tj] = __builtin_amdgcn_mfma_f32_16x16x32_bf16(qa.v, kb.v, accQK[tj], 0, 0, 0);
        }
    }
    __syncthreads();   // lamL/betaL/dlL visible
    // mask + scale; Am -> LDS fp32, P -> global bf16
#pragma unroll
    for (int tj = 0; tj < 4; tj++) {
#pragma unroll
        for (int r = 0; r < 4; r++) {
            int ti_ = w * 16 + quad * 4 + r;
            int j = tj * 16 + l15;
            float e = (j <= ti_) ? expf(Gs[ti_] - Gs[j]) : 0.f;
            Am[ti_ * 66 + j] = (j < ti_) ? betaL[ti_] * e * accKK[tj][r] : 0.f;
            Pbuf[(long)cid * 4096 + ti_ * 64 + j] =
                (j <= ti_) ? f2bf(GDN_SCALE * e * accQK[tj][r]) : (u16)0;
        }
    }
    // wbq, qlq (row-major [64][128])
    {
        int row = t >> 2, seg = (t & 3) * 32;
        float sw = -betaL[row] * lamL[row];
        float sq = GDN_SCALE * lamL[row];
#pragma unroll
        for (int c0 = 0; c0 < 32; c0 += 8) {
            u16 wt[8], qt2[8];
#pragma unroll
            for (int j2 = 0; j2 < 8; j2++) {
                wt[j2]  = f2bf(sw * bf2f(Kl[row * 136 + seg + c0 + j2]));
                qt2[j2] = f2bf(sq * bf2f(Ql[row * 136 + seg + c0 + j2]));
            }
            *(uint4*)&wbq[(long)cid * 8192 + row * 128 + seg + c0] = *(uint4*)wt;
            *(uint4*)&qlq[(long)cid * 8192 + row * 128 + seg + c0] = *(uint4*)qt2;
        }
    }
    // kdq (transposed [128 k][64 t]) — all 256 threads
    {
        int k = t & 127, t0b = (t >> 7) * 32;
#pragma unroll
        for (int t0 = 0; t0 < 32; t0 += 8) {
            u16 tmp[8];
#pragma unroll
            for (int j2 = 0; j2 < 8; j2++)
                tmp[j2] = f2bf(dlL[t0b + t0 + j2] * bf2f(Kl[(t0b + t0 + j2) * 136 + k]));
            *(uint4*)&kdq[(long)cid * 8192 + k * 64 + t0b + t0] = *(uint4*)tmp;
        }
    }
    __syncthreads();
    // fwd-subst: T11 (lanes 0-31 of wave 0), T22 (lanes 0-31 of wave 1), zero T12
    if (t < 32) {
        int c = t;
        for (int i = 0; i < 32; i++) {
            float s = (i == c) ? 1.f : 0.f;
            for (int j = 0; j < i; j++) s -= Am[i * 66 + j] * Tm[j * 66 + c];
            Tm[i * 66 + c] = s;
        }
    } else if (t >= 64 && t < 96) {
        int c = 32 + (t - 64);
        for (int i = 32; i < 64; i++) {
            float s = (i == c) ? 1.f : 0.f;
            for (int j = 32; j < i; j++) s -= Am[i * 66 + j] * Tm[j * 66 + c];
            Tm[i * 66 + c] = s;
        }
    } else if (t >= 128 && t < 192) {
        int idx = t - 128;
        for (int kk = 0; kk < 16; kk++) {
            int e = idx * 16 + kk;
            Tm[(e >> 5) * 66 + 32 + (e & 31)] = 0.f;
        }
    }
    __syncthreads();
    {   // Tt = A21 * T11  (32x32, 4 elems/thread)
        int e0 = t * 4;
#pragma unroll
        for (int kk = 0; kk < 4; kk++) {
            int e = e0 + kk; int i = e >> 5, c = e & 31;
            float s = 0.f;
            for (int j = 0; j < 32; j++) s += Am[(32 + i) * 66 + j] * Tm[j * 66 + c];
            Tt[i * 33 + c] = s;
        }
    }
    __syncthreads();
    {   // T21 = -T22 * Tt
        int e0 = t * 4;
#pragma unroll
        for (int kk = 0; kk < 4; kk++) {
            int e = e0 + kk; int i = e >> 5, c = e & 31;
            float s = 0.f;
            for (int j = 0; j < 32; j++) s -= Tm[(32 + i) * 66 + 32 + j] * Tt[j * 33 + c];
            Tm[(32 + i) * 66 + c] = s;
        }
    }
    __syncthreads();
    {   // T -> global bf16
        int row = t >> 2, c0 = (t & 3) * 16;
        u16 tmp[16];
#pragma unroll
        for (int i = 0; i < 16; i++) tmp[i] = f2bf(Tm[row * 66 + c0 + i]);
        *(uint4*)&Tbuf[(long)cid * 4096 + row * 64 + c0]     = *(uint4*)tmp;
        *(uint4*)&Tbuf[(long)cid * 4096 + row * 64 + c0 + 8] = *(uint4*)(tmp + 8);
    }
}

// ---------------- gdn_chunk v3: direct-global fragments, 512 blocks ----------
// 512 blocks = (bh=64) x (dc=8: 16 v-cols). 256 threads (4 waves).
// T/P/wb/ql/kd fragments loaded global->VGPR (each read once per block);
// only block-produced tiles (S0 split, vb/O, rhsT, DT) live in LDS (~19 KB).
// S0^T in registers: wave w owns k-tiles {2w,2w+1} (all 16 v rows).
__global__ __launch_bounds__(256) void gdn_chunk(
    const u16* __restrict__ vs_g, const float* __restrict__ b_g,
    const u16* __restrict__ Tq, const u16* __restrict__ Pq,
    const u16* __restrict__ wbq, const u16* __restrict__ qlq,
    const u16* __restrict__ kdq, const float* __restrict__ gam_g,
    float* __restrict__ o_g) {
    int bid = blockIdx.x;
    int dc = bid & 7;
    int bh = bid >> 3;
    int b = bh >> 4, h = bh & 15;
    int t = threadIdx.x;
    int lane = t & 63, w = t >> 6, l15 = lane & 15, quad = lane >> 4;

    __shared__ u16 s0h[16 * 136], s0l[16 * 136];   // S0^T [v][k] hi/lo
    __shared__ float vO[64 * 20];                  // vb / O, [t][v]
    __shared__ u16 rhsT[16 * 72], DT[16 * 72];     // [v][t]

    float4v S0r[2];
    S0r[0] = (float4v){0.f, 0.f, 0.f, 0.f};
    S0r[1] = (float4v){0.f, 0.f, 0.f, 0.f};

    const int orow = t >> 2, oseg = (t & 3) * 4;   // 64 rows x 16 cols

    for (int ch = 0; ch < 16; ch++) {
        int cid = bh * 16 + ch;
        long rowbase = (long)bh * L_SEQ + ch * 64;
        float gam = gam_g[cid];

        // prefetch wb fragments (used phase b)
        const u16* wbp = wbq + (long)cid * 8192 + (w * 16 + l15) * 128 + quad * 8;
        uint4 wbf0 = *(const uint4*)(wbp);
        uint4 wbf1 = *(const uint4*)(wbp + 32);
        uint4 wbf2 = *(const uint4*)(wbp + 64);
        uint4 wbf3 = *(const uint4*)(wbp + 96);

        // ---- phase a: store prev O, load vb, split S0 ----
        if (ch > 0) {
            float4 a = *(const float4*)&vO[orow * 20 + oseg];
            float* d2 = o_g + (((long)b * L_SEQ + (ch - 1) * 64 + orow) * 16 + h) * 128L
                        + dc * 16 + oseg;
            *(float4*)d2 = a;
        }
        {
            float beta = b_g[rowbase + orow];
            uint2 vv = *(const uint2*)(vs_g + (rowbase + orow) * DV + dc * 16 + oseg);
            const u16* vp = (const u16*)&vv;
#pragma unroll
            for (int j2 = 0; j2 < 4; j2++)
                vO[orow * 20 + oseg + j2] = beta * bf2f(vp[j2]);
        }
#pragma unroll
        for (int ktl = 0; ktl < 2; ktl++) {
            int kc = (2 * w + ktl) * 16 + l15;
#pragma unroll
            for (int r = 0; r < 4; r++) {
                float x = S0r[ktl][r];
                u16 hi = f2bf(x);
                float lo = x - bf2f(hi);
                s0h[(quad * 4 + r) * 136 + kc] = hi;
                s0l[(quad * 4 + r) * 136 + kc] = f2bf(lo);
            }
        }
        __syncthreads();

        // ---- phase b: RHS[t][v] = vb + wb*(S0h+S0l) -> rhsT ----
        const u16* Tp = Tq + (long)cid * 4096 + (w * 16 + l15) * 64 + quad * 8;
        uint4 Tf0 = *(const uint4*)(Tp);        // prefetch for phase c
        uint4 Tf1 = *(const uint4*)(Tp + 32);
        {
            float4v acc;
#pragma unroll
            for (int r = 0; r < 4; r++)
                acc[r] = vO[(w * 16 + quad * 4 + r) * 20 + l15];
            uint4 wbf[4] = {wbf0, wbf1, wbf2, wbf3};
#pragma unroll
            for (int k0 = 0; k0 < 4; k0++) {
                FragU a, bh_, bl_;
                a.u = wbf[k0];
                bh_.u = *(const uint4*)&s0h[l15 * 136 + k0 * 32 + quad * 8];
                acc = __builtin_amdgcn_mfma_f32_16x16x32_bf16(a.v, bh_.v, acc, 0, 0, 0);
                bl_.u = *(const uint4*)&s0l[l15 * 136 + k0 * 32 + quad * 8];
                acc = __builtin_amdgcn_mfma_f32_16x16x32_bf16(a.v, bl_.v, acc, 0, 0, 0);
            }
            u16 tmp[4] = {f2bf(acc[0]), f2bf(acc[1]), f2bf(acc[2]), f2bf(acc[3])};
            *(uint2*)&rhsT[l15 * 72 + w * 16 + quad * 4] = *(uint2*)tmp;
        }
        __syncthreads();

        // ---- phase c: D = T*RHS -> DT ----
        const u16* qlp = qlq + (long)cid * 8192 + (w * 16 + l15) * 128 + quad * 8;
        uint4 qlf0 = *(const uint4*)(qlp);      // prefetch for phase d
        uint4 qlf1 = *(const uint4*)(qlp + 32);
        uint4 qlf2 = *(const uint4*)(qlp + 64);
        uint4 qlf3 = *(const uint4*)(qlp + 96);
        const u16* Pp = Pq + (long)cid * 4096 + (w * 16 + l15) * 64 + quad * 8;
        uint4 Pf0 = *(const uint4*)(Pp);
        uint4 Pf1 = *(const uint4*)(Pp + 32);
        {
            float4v acc = (float4v){0.f, 0.f, 0.f, 0.f};
            uint4 Tf[2] = {Tf0, Tf1};
#pragma unroll
            for (int k0 = 0; k0 < 2; k0++) {
                FragU a, b_;
                a.u = Tf[k0];
                b_.u = *(const uint4*)&rhsT[l15 * 72 + k0 * 32 + quad * 8];
                acc = __builtin_amdgcn_mfma_f32_16x16x32_bf16(a.v, b_.v, acc, 0, 0, 0);
            }
            u16 tmp[4] = {f2bf(acc[0]), f2bf(acc[1]), f2bf(acc[2]), f2bf(acc[3])};
            *(uint2*)&DT[l15 * 72 + w * 16 + quad * 4] = *(uint2*)tmp;
        }
        __syncthreads();

        // ---- phase d: O = ql*S0 + P*D ; S0 = gam*S0 + kd^T D ----
        uint4 kdf[2][2];
#pragma unroll
        for (int ktl = 0; ktl < 2; ktl++) {
            const u16* kdp = kdq + (long)cid * 8192 + ((2 * w + ktl) * 16 + l15) * 64 + quad * 8;
            kdf[ktl][0] = *(const uint4*)(kdp);
            kdf[ktl][1] = *(const uint4*)(kdp + 32);
        }
        {
            float4v acc = (float4v){0.f, 0.f, 0.f, 0.f};
            uint4 qlf[4] = {qlf0, qlf1, qlf2, qlf3};
#pragma unroll
            for (int k0 = 0; k0 < 4; k0++) {
                FragU a, bh_, bl_;
                a.u = qlf[k0];
                bh_.u = *(const uint4*)&s0h[l15 * 136 + k0 * 32 + quad * 8];
                acc = __builtin_amdgcn_mfma_f32_16x16x32_bf16(a.v, bh_.v, acc, 0, 0, 0);
                bl_.u = *(const uint4*)&s0l[l15 * 136 + k0 * 32 + quad * 8];
                acc = __builtin_amdgcn_mfma_f32_16x16x32_bf16(a.v, bl_.v, acc, 0, 0, 0);
            }
            uint4 Pf[2] = {Pf0, Pf1};
#pragma unroll
            for (int k0 = 0; k0 < 2; k0++) {
                FragU a, b_;
                a.u = Pf[k0];
                b_.u = *(const uint4*)&DT[l15 * 72 + k0 * 32 + quad * 8];
                acc = __builtin_amdgcn_mfma_f32_16x16x32_bf16(a.v, b_.v, acc, 0, 0, 0);
            }
#pragma unroll
            for (int r = 0; r < 4; r++)
                vO[(w * 16 + quad * 4 + r) * 20 + l15] = acc[r];
        }
#pragma unroll
        for (int ktl = 0; ktl < 2; ktl++) {
            float4v acc = S0r[ktl];
#pragma unroll
            for (int r = 0; r < 4; r++) acc[r] *= gam;
#pragma unroll
            for (int t0 = 0; t0 < 2; t0++) {
                FragU a, b_;
                a.u = *(const uint4*)&DT[l15 * 72 + t0 * 32 + quad * 8];
                b_.u = kdf[ktl][t0];
                acc = __builtin_amdgcn_mfma_f32_16x16x32_bf16(a.v, b_.v, acc, 0, 0, 0);
            }
            S0r[ktl] = acc;
        }
        __syncthreads();
    }
    // final chunk's O store
    {
        float4 a = *(const float4*)&vO[orow * 20 + oseg];
        float* d2 = o_g + (((long)b * L_SEQ + 15 * 64 + orow) * 16 + h) * 128L
                    + dc * 16 + oseg;
        *(float4*)d2 = a;
    }
}

// ---------------- gated RMS norm -> bf16 A2 ----------------------------------
__global__ __launch_bounds__(128) void gated_norm(
    const float* __restrict__ o, const u16* __restrict__ qkvz,
    const float* __restrict__ norm_w, u16* __restrict__ A2) {
    int bid = blockIdx.x;  // (b*L+l)*16 + h
    int t = threadIdx.x;   // 0..127
    float ov = o[(long)bid * 128 + t];
    float s = ov * ov;
#pragma unroll
    for (int off = 32; off > 0; off >>= 1) s += __shfl_down(s, off);
    __shared__ float ws2[2];
    if ((t & 63) == 0) ws2[t >> 6] = s;
    __syncthreads();
    float tot = ws2[0] + ws2[1];
    float rinv = rsqrtf(tot * (1.f / 128.f) + 1e-6f);
    int bl = bid >> 4, h = bid & 15;
    float z = bf2f(qkvz[(long)bl * NQKVZ + CONV_DIM + h * 128 + t]);
    float sig = 1.f / (1.f + expf(-z));
    float val = ov * rinv * norm_w[t] * sig;
    A2[(long)bl * 2048 + h * 128 + t] = f2bf(val);
}

// ---------------- host-side launcher -----------------------------------------
extern "C" void kernel_launch(void* const* d_in, const int* in_sizes, int n_in,
                              void* d_out, int out_size, void* d_ws, size_t ws_size,
                              hipStream_t stream) {
    const float* hs    = (const float*)d_in[0];
    const float* Wqkvz = (const float*)d_in[1];
    const float* Wba   = (const float*)d_in[2];
    const float* convw = (const float*)d_in[3];
    const float* convb = (const float*)d_in[4];
    const float* A_log = (const float*)d_in[5];
    const float* dtb   = (const float*)d_in[6];
    const float* normw = (const float*)d_in[7];
    const float* Wout  = (const float*)d_in[8];

    char* ws = (char*)d_ws;
    size_t off = 0;
    auto alloc = [&](size_t bytes) {
        size_t o = off;
        off = (off + bytes + 255) & ~(size_t)255;
        return o;
    };
    // region0: WqkvzT (bf16) — dead after GEMM1, reused for os (fp32)
    size_t r0 = alloc((size_t)NQKVZ * HID * 2);
    // region1: hs_bf16 — kept through ba_gemm; A2 aliases after
    size_t r1 = alloc((size_t)4096 * HID * 2);
    u16*   WqkvzT = (u16*)(ws + r0);
    float* os     = (float*)(ws + r0);
    u16*   hsb    = (u16*)(ws + r1);
    u16*   A2     = (u16*)(ws + r1);   // written by gated_norm after ba_gemm done
    u16*   qkvz   = (u16*)(ws + alloc((size_t)4096 * NQKVZ * 2));
    u16*   qs     = (u16*)(ws + alloc((size_t)64 * L_SEQ * DK * 2));
    u16*   ks     = (u16*)(ws + alloc((size_t)64 * L_SEQ * DK * 2));
    u16*   vs     = (u16*)(ws + alloc((size_t)64 * L_SEQ * DV * 2));
    float* gs     = (float*)(ws + alloc((size_t)64 * L_SEQ * 4));
    float* bs     = (float*)(ws + alloc((size_t)64 * L_SEQ * 4));
    u16*   WoutT  = (u16*)(ws + alloc((size_t)HID * 2048 * 2));
    u16*   WbaTb  = (u16*)(ws + alloc((size_t)32 * HID * 2));
    u16*   Tbuf   = (u16*)(ws + alloc((size_t)1024 * 4096 * 2));
    u16*   Pbuf   = (u16*)(ws + alloc((size_t)1024 * 4096 * 2));
    u16*   wbq    = (u16*)(ws + alloc((size_t)1024 * 8192 * 2));
    u16*   qlq    = (u16*)(ws + alloc((size_t)1024 * 8192 * 2));
    u16*   kdq    = (u16*)(ws + alloc((size_t)1024 * 8192 * 2));
    float* gamb   = (float*)(ws + alloc((size_t)1024 * 4));

    // 1. convert + transposes
    hipLaunchKernelGGL(f32_to_bf16, dim3(4096), dim3(256), 0, stream, hs, hsb);
    hipLaunchKernelGGL(transpose_f32_bf16, dim3(NQKVZ / 32, HID / 32), dim3(256), 0, stream,
                       Wqkvz, WqkvzT, HID, NQKVZ);
    hipLaunchKernelGGL(transpose_f32_bf16, dim3(2048 / 32, 2048 / 32), dim3(256), 0, stream,
                       Wout, WoutT, 2048, 2048);
    hipLaunchKernelGGL(transpose_f32_bf16, dim3(1, HID / 32), dim3(256), 0, stream,
                       Wba, WbaTb, HID, 32);

    // 2. GEMM1: qkvz = hs @ W_qkvz (256x256 4-phase deep counted-vmcnt)
    hipLaunchKernelGGL(gemm1_8ph, dim3(512), dim3(512), 0, stream,
                       hsb, WqkvzT, qkvz);

    // 3. ba (MFMA) -> g, beta
    hipLaunchKernelGGL(ba_gemm, dim3(64), dim3(256), 0, stream,
                       hsb, WbaTb, A_log, dtb, gs, bs);

    // 4. conv + l2norm -> q,k,v (bf16)
    hipLaunchKernelGGL(conv_qkv, dim3(4096), dim3(256), 0, stream,
                       qkvz, convw, convb, qs, ks, vs);

    // 5a. chunk prep (parallel): T, P, wb, ql, kd, gam
    hipLaunchKernelGGL(gdn_prep, dim3(1024), dim3(256), 0, stream,
                       ks, qs, gs, bs, Tbuf, Pbuf, wbq, qlq, kdq, gamb);

    // 5b. chunk recurrence (MFMA, direct-global fragments, 512 blocks)
    hipLaunchKernelGGL(gdn_chunk, dim3(512), dim3(256), 0, stream,
                       vs, bs, Tbuf, Pbuf, wbq, qlq, kdq, gamb, os);

    // 6. gated RMS norm -> bf16 A2
    hipLaunchKernelGGL(gated_norm, dim3(4096 * NH), dim3(128), 0, stream,
                       os, qkvz, normw, A2);

    // 7. GEMM2: out = A2 @ W_out (256x128 2-phase counted-vmcnt)
    hipLaunchKernelGGL(gemm2_2ph, dim3(256), dim3(512), 0, stream,
                       A2, WoutT, (float*)d_out);
}

// Round 4
// 559.751 us; speedup vs baseline: 1.1085x; 1.1085x over previous
//
#include <hip/hip_runtime.h>

typedef unsigned short u16;
typedef unsigned int u32;
typedef short short8 __attribute__((ext_vector_type(8)));
typedef float float4v __attribute__((ext_vector_type(4)));

#define L_SEQ 1024
#define NB 4
#define NH 16
#define DK 128
#define DV 128
#define HID 2048
#define NQKVZ 8192
#define CONV_DIM 6144
#define GDN_SCALE 0.08838834764831845f  // 128^-0.5

static __device__ __forceinline__ float bf2f(u16 u) {
    union { u32 i; float f; } x; x.i = ((u32)u) << 16; return x.f;
}
static __device__ __forceinline__ u16 f2bf(float f) {
    union { float f; u32 u; } x; x.f = f;
    u32 r = x.u + 0x7FFF + ((x.u >> 16) & 1);
    return (u16)(r >> 16);
}

union FragU { short8 v; uint4 u; };

// async global->LDS, 16B per lane (lane-contiguous LDS dest required).
#define GLOAD_LDS16(g, l)                                        \
    __builtin_amdgcn_global_load_lds(                            \
        (const __attribute__((address_space(1))) void*)(g),      \
        (__attribute__((address_space(3))) void*)(l), 16, 0, 0)

// ---------------- fp32 -> bf16 elementwise convert ---------------------------
__global__ __launch_bounds__(256) void f32_to_bf16(
    const float* __restrict__ in, u16* __restrict__ out) {
    long i = ((long)blockIdx.x * 256 + threadIdx.x) * 8;
    float4 a = *(const float4*)(in + i);
    float4 b = *(const float4*)(in + i + 4);
    u16 tmp[8];
    tmp[0] = f2bf(a.x); tmp[1] = f2bf(a.y); tmp[2] = f2bf(a.z); tmp[3] = f2bf(a.w);
    tmp[4] = f2bf(b.x); tmp[5] = f2bf(b.y); tmp[6] = f2bf(b.z); tmp[7] = f2bf(b.w);
    *(uint4*)(out + i) = *(const uint4*)tmp;
}

// ---------------- transpose fp32 (RxC) -> bf16 (CxR) -------------------------
__global__ __launch_bounds__(256) void transpose_f32_bf16(
    const float* __restrict__ in, u16* __restrict__ out, int R, int C) {
    __shared__ float tile[32][33];
    int bx = blockIdx.x, by = blockIdx.y;
    int c = threadIdx.x & 31;
    int r0 = threadIdx.x >> 5;
#pragma unroll
    for (int i = 0; i < 4; i++) {
        int r = r0 + i * 8;
        tile[r][c] = in[(long)(by * 32 + r) * C + bx * 32 + c];
    }
    __syncthreads();
#pragma unroll
    for (int i = 0; i < 4; i++) {
        int r = r0 + i * 8;
        out[(long)(bx * 32 + r) * R + by * 32 + c] = f2bf(tile[c][r]);
    }
}

// ---------------- GEMM (m97 structure): C = A * BT^T, bf16 in, OutT out ------
#define BM 128
#define BN 128
#define BKK 32

static __device__ __forceinline__ void store_out(u16* p, float v)  { *p = f2bf(v); }
static __device__ __forceinline__ void store_out(float* p, float v){ *p = v; }

template <typename OutT>
__global__ __launch_bounds__(256) void gemm_abT(
    const u16* __restrict__ A, const u16* __restrict__ BT,
    OutT* __restrict__ C, int M, int N, int K) {
    __shared__ u16 As[BM * BKK];
    __shared__ u16 Bs[BN * BKK];
    int t = threadIdx.x;
    int lane = t & 63;
    int w = t >> 6;
    int wm = (w & 1) * 64;
    int wn = (w >> 1) * 64;
    int l15 = lane & 15;
    int quad = lane >> 4;
    long blockM = (long)blockIdx.y * BM;
    long blockN = (long)blockIdx.x * BN;

    float4v acc[4][4];
#pragma unroll
    for (int i = 0; i < 4; i++)
#pragma unroll
        for (int j = 0; j < 4; j++) acc[i][j] = (float4v){0.f, 0.f, 0.f, 0.f};

    const u16* Ab = A + blockM * K;
    const u16* Bb = BT + blockN * K;

    const int r0 = t >> 2,         c0 = (t & 3) * 8;
    const int r1 = (t + 256) >> 2, c1 = ((t + 256) & 3) * 8;
    u16* As0 = As + t * 8;         u16* As1 = As + (t + 256) * 8;
    u16* Bs0 = Bs + t * 8;         u16* Bs1 = Bs + (t + 256) * 8;
    const u16* Ag0 = Ab + (long)r0 * K + c0;
    const u16* Ag1 = Ab + (long)r1 * K + c1;
    const u16* Bg0 = Bb + (long)r0 * K + c0;
    const u16* Bg1 = Bb + (long)r1 * K + c1;

    for (int k0 = 0; k0 < K; k0 += BKK) {
        __syncthreads();
        GLOAD_LDS16(Ag0 + k0, As0);
        GLOAD_LDS16(Ag1 + k0, As1);
        GLOAD_LDS16(Bg0 + k0, Bs0);
        GLOAD_LDS16(Bg1 + k0, Bs1);
        __syncthreads();

        FragU fa[4], fb[4];
#pragma unroll
        for (int i = 0; i < 4; i++) {
            fa[i].u = *(const uint4*)(As + (wm + i * 16 + l15) * BKK + quad * 8);
            fb[i].u = *(const uint4*)(Bs + (wn + i * 16 + l15) * BKK + quad * 8);
        }
#pragma unroll
        for (int i = 0; i < 4; i++)
#pragma unroll
            for (int j = 0; j < 4; j++)
                acc[i][j] = __builtin_amdgcn_mfma_f32_16x16x32_bf16(
                    fa[i].v, fb[j].v, acc[i][j], 0, 0, 0);
    }

#pragma unroll
    for (int i = 0; i < 4; i++) {
        long mrow = blockM + wm + i * 16 + quad * 4;
#pragma unroll
        for (int j = 0; j < 4; j++) {
            long col = blockN + wn + j * 16 + l15;
#pragma unroll
            for (int r = 0; r < 4; r++) {
                store_out(&C[(mrow + r) * N + col], acc[i][j][r]);
            }
        }
    }
}

// ---------------- GEMM1: 256x256 tile, BK=64, m201-style 4-phase groups ------
// (r2 schedule, measured 130 us / MfmaUtil 47.6 — r3 remap regressed, reverted)
// 8 waves (2M x 4N), 512 threads. LDS = 2 dbuf x (A 256x64 + B 256x64) bf16
// = 128 KB. Per K-tile group of 4 phases, each phase:
//   {ds_read quadrant frags | stage 2 x global_load_lds (one 64x64 quarter) |
//    s_barrier | lgkmcnt(0) | setprio(1) | 16 MFMA | setprio(0)}
// Stagger: ph1 stages next-tile Aq1,Aq3; ph2 Bq0,Bq1; ph3 Bq2,Bq3 (-> other
// dbuf); ph4 stages next-NEXT tile Aq0,Aq2 into the CURRENT dbuf (those rows
// died at ph1, >=2 barriers earlier). One counted vmcnt(2) per group.
// Swizzle: 16B chunk ^= row&7, pre-swizzled global source + swizzled ds_read.
#define G1_LDSU 32768  // u16 per dbuf (64 KB)

__global__ __launch_bounds__(512, 2) void gemm1_8ph(
    const u16* __restrict__ A, const u16* __restrict__ BT,
    u16* __restrict__ C) {
    const int K = HID, N = NQKVZ;
    __shared__ __align__(16) u16 lds[2 * G1_LDSU];  // 128 KB

    int t = threadIdx.x;
    int lane = t & 63, w = t >> 6, l15 = lane & 15, quad = lane >> 4;
    int wm = w & 1, wn = w >> 1;

    // XCD patch swizzle: 512 wgs, XCD = orig&7 owns patch of 8x8 tiles
    int orig = blockIdx.x;
    int wg = (orig & 7) * 64 + (orig >> 3);
    int p = wg >> 6, q = wg & 63;
    long blockM = (long)((p >> 2) * 8 + (q >> 3)) * 256;  // 0..15
    long blockN = (long)((p & 3) * 8 + (q & 7)) * 256;    // 0..31

    // staging: thread t covers (row-in-quarter = t>>3, chunk = t&7);
    // global chunk pre-swizzled so LDS dest stays lane-linear.
    int srow = t >> 3;
    int scol = ((t & 7) ^ (srow & 7)) * 8;
    const u16* Ast = A + (blockM + srow) * (long)K + scol;
    const u16* Bst = BT + (blockN + srow) * (long)K + scol;

    // A quarter q (64 rows) at dbuf*G1_LDSU + q*4096; B at +16384 + q*4096.
#define STA(db, qq, T) GLOAD_LDS16(Ast + (long)(qq) * 64 * K + (T) * 64,      \
                                   lds + (db) * G1_LDSU + (qq) * 4096 + t * 8)
#define STB(db, qq, T) GLOAD_LDS16(Bst + (long)(qq) * 64 * K + (T) * 64,      \
                                   lds + (db) * G1_LDSU + 16384 + (qq) * 4096 + t * 8)

    // fragment read offsets (u16 units): row*64 + ((kc)^(row&7))*8
    const int rowA0 = (wm * 128 + l15) * 64;
    const int rowB0 = 16384 + (wn * 64 + l15) * 64;
    const int cs0 = ((quad) ^ (l15 & 7)) * 8;        // kk=0 chunk
    const int cs1 = ((4 + quad) ^ (l15 & 7)) * 8;    // kk=1 chunk

    float4v acc[8][4];
#pragma unroll
    for (int mi = 0; mi < 8; mi++)
#pragma unroll
        for (int nj = 0; nj < 4; nj++) acc[mi][nj] = (float4v){0.f, 0.f, 0.f, 0.f};

    // prologue: all of T0 -> dbuf0; T1 Aq0,Aq2 -> dbuf1. 10 loads, drain to 4.
    STA(0, 0, 0); STA(0, 1, 0); STA(0, 2, 0); STA(0, 3, 0);
    STB(0, 0, 0); STB(0, 1, 0); STB(0, 2, 0); STB(0, 3, 0);
    STA(1, 0, 1); STA(1, 2, 1);
    asm volatile("s_waitcnt vmcnt(2)" ::: "memory");
    __builtin_amdgcn_s_barrier();

    FragU bA[4][2], bB0[2][2], bB1[2][2];

    for (int g = 0; g < 32; ++g) {
        const int c = g & 1, db = c ^ 1;
        const u16* sb = lds + c * G1_LDSU;

        // ---- ph1 (mh0,nh0): 8 A-reads + 4 B-reads; stage T(g+1).Aq1,Aq3 ----
#pragma unroll
        for (int i = 0; i < 4; i++) {
            bA[i][0].u = *(const uint4*)(sb + rowA0 + i * 1024 + cs0);
            bA[i][1].u = *(const uint4*)(sb + rowA0 + i * 1024 + cs1);
        }
#pragma unroll
        for (int j = 0; j < 2; j++) {
            bB0[j][0].u = *(const uint4*)(sb + rowB0 + j * 1024 + cs0);
            bB0[j][1].u = *(const uint4*)(sb + rowB0 + j * 1024 + cs1);
        }
        if (g + 1 < 32) { STA(db, 1, g + 1); STA(db, 3, g + 1); }
        __builtin_amdgcn_s_barrier();
        asm volatile("s_waitcnt lgkmcnt(0)" ::: "memory");
        __builtin_amdgcn_s_setprio(1);
#pragma unroll
        for (int i = 0; i < 4; i++)
#pragma unroll
            for (int j = 0; j < 2; j++) {
                acc[i][j] = __builtin_amdgcn_mfma_f32_16x16x32_bf16(
                    bA[i][0].v, bB0[j][0].v, acc[i][j], 0, 0, 0);
                acc[i][j] = __builtin_amdgcn_mfma_f32_16x16x32_bf16(
                    bA[i][1].v, bB0[j][1].v, acc[i][j], 0, 0, 0);
            }
        __builtin_amdgcn_s_setprio(0);

        // ---- ph2 (mh0,nh1): 4 B-reads; stage T(g+1).Bq0,Bq1 ----
#pragma unroll
        for (int j = 0; j < 2; j++) {
            bB1[j][0].u = *(const uint4*)(sb + rowB0 + (2 + j) * 1024 + cs0);
            bB1[j][1].u = *(const uint4*)(sb + rowB0 + (2 + j) * 1024 + cs1);
        }
        if (g + 1 < 32) { STB(db, 0, g + 1); STB(db, 1, g + 1); }
        __builtin_amdgcn_s_barrier();
        asm volatile("s_waitcnt lgkmcnt(0)" ::: "memory");
        __builtin_amdgcn_s_setprio(1);
#pragma unroll
        for (int i = 0; i < 4; i++)
#pragma unroll
            for (int j = 0; j < 2; j++) {
                acc[i][2 + j] = __builtin_amdgcn_mfma_f32_16x16x32_bf16(
                    bA[i][0].v, bB1[j][0].v, acc[i][2 + j], 0, 0, 0);
                acc[i][2 + j] = __builtin_amdgcn_mfma_f32_16x16x32_bf16(
                    bA[i][1].v, bB1[j][1].v, acc[i][2 + j], 0, 0, 0);
            }
        __builtin_amdgcn_s_setprio(0);

        // ---- ph3 (mh1,nh0): 8 A-reads; stage T(g+1).Bq2,Bq3 ----
#pragma unroll
        for (int i = 0; i < 4; i++) {
            bA[i][0].u = *(const uint4*)(sb + rowA0 + (4 + i) * 1024 + cs0);
            bA[i][1].u = *(const uint4*)(sb + rowA0 + (4 + i) * 1024 + cs1);
        }
        if (g + 1 < 32) { STB(db, 2, g + 1); STB(db, 3, g + 1); }
        __builtin_amdgcn_s_barrier();
        asm volatile("s_waitcnt lgkmcnt(0)" ::: "memory");
        __builtin_amdgcn_s_setprio(1);
#pragma unroll
        for (int i = 0; i < 4; i++)
#pragma unroll
            for (int j = 0; j < 2; j++) {
                acc[4 + i][j] = __builtin_amdgcn_mfma_f32_16x16x32_bf16(
                    bA[i][0].v, bB0[j][0].v, acc[4 + i][j], 0, 0, 0);
                acc[4 + i][j] = __builtin_amdgcn_mfma_f32_16x16x32_bf16(
                    bA[i][1].v, bB0[j][1].v, acc[4 + i][j], 0, 0, 0);
            }
        __builtin_amdgcn_s_setprio(0);

        // ---- ph4 (mh1,nh1): 0 reads; stage T(g+2).Aq0,Aq2 into CURRENT dbuf
        // (c.Aq0/Aq2 last read at ph1, two barriers ago). ----
        if (g + 2 < 32) { STA(c, 0, g + 2); STA(c, 2, g + 2); }
        __builtin_amdgcn_s_barrier();
        __builtin_amdgcn_s_setprio(1);
#pragma unroll
        for (int i = 0; i < 4; i++)
#pragma unroll
            for (int j = 0; j < 2; j++) {
                acc[4 + i][2 + j] = __builtin_amdgcn_mfma_f32_16x16x32_bf16(
                    bA[i][0].v, bB1[j][0].v, acc[4 + i][2 + j], 0, 0, 0);
                acc[4 + i][2 + j] = __builtin_amdgcn_mfma_f32_16x16x32_bf16(
                    bA[i][1].v, bB1[j][1].v, acc[4 + i][2 + j], 0, 0, 0);
            }
        __builtin_amdgcn_s_setprio(0);

        // group end: counted wait (never 0 until the tail)
        if (g < 30)       { asm volatile("s_waitcnt vmcnt(2)" ::: "memory"); }
        else if (g == 30) { asm volatile("s_waitcnt vmcnt(0)" ::: "memory"); }
        __builtin_amdgcn_s_barrier();
    }

    // epilogue: C[row][col]
#pragma unroll
    for (int mi = 0; mi < 8; mi++) {
        long row0 = blockM + wm * 128 + mi * 16 + quad * 4;
#pragma unroll
        for (int nj = 0; nj < 4; nj++) {
            long col = blockN + wn * 64 + nj * 16 + l15;
#pragma unroll
            for (int r = 0; r < 4; r++)
                C[(row0 + r) * N + col] = f2bf(acc[mi][nj][r]);
        }
    }
#undef STA
#undef STB
}

// ---------------- GEMM2: 256x128 tile, BK=64, 2-phase, counted vmcnt ---------
// 256 wgs (1/CU), 8 waves (2M x 4N -> per-wave 128x32), 96 KB LDS.
#define G2_LDSU 24576  // u16 per dbuf (48 KB)

__global__ __launch_bounds__(512) void gemm2_2ph(
    const u16* __restrict__ A, const u16* __restrict__ BT,
    float* __restrict__ C) {
    const int K = HID, N = 2048;
    __shared__ __align__(16) u16 lds[2 * G2_LDSU];  // 96 KB

    int t = threadIdx.x;
    int lane = t & 63, w = t >> 6, l15 = lane & 15, quad = lane >> 4;
    int wm = w & 1, wn = w >> 1;

    // XCD swizzle: 256 wgs; XCD x owns an 8Mx4N tile patch.
    int orig = blockIdx.x;
    int x = orig & 7, q = orig >> 3;           // q in 0..31
    long blockM = (long)((x >> 2) * 8 + (q >> 2)) * 256;   // 0..15
    long blockN = (long)((x & 3) * 4 + (q & 3)) * 128;     // 0..15

    int srow = t >> 3;
    int scol = ((t & 7) ^ (srow & 7)) * 8;
    const u16* Ast = A + (blockM + srow) * (long)K + scol;
    const u16* Bst = BT + (blockN + srow) * (long)K + scol;

#define STA2(db, qq, T) GLOAD_LDS16(Ast + (long)(qq) * 64 * K + (T) * 64,     \
                                    lds + (db) * G2_LDSU + (qq) * 4096 + t * 8)
#define STB2(db, hh, T) GLOAD_LDS16(Bst + (long)(hh) * 64 * K + (T) * 64,     \
                                    lds + (db) * G2_LDSU + 16384 + (hh) * 4096 + t * 8)

    const int cs0 = ((quad) ^ (l15 & 7)) * 8;
    const int cs1 = ((4 + quad) ^ (l15 & 7)) * 8;
    int offA[8], offB[2];
#pragma unroll
    for (int mi = 0; mi < 8; mi++)
        offA[mi] = (wm * 2 + (mi >> 2)) * 4096 + (((mi & 3) * 16 + l15)) * 64;
#pragma unroll
    for (int nj = 0; nj < 2; nj++)
        offB[nj] = 16384 + (wn >> 1) * 4096 + ((wn & 1) * 32 + nj * 16 + l15) * 64;

    float4v acc[8][2];
#pragma unroll
    for (int mi = 0; mi < 8; mi++)
#pragma unroll
        for (int nj = 0; nj < 2; nj++) acc[mi][nj] = (float4v){0.f, 0.f, 0.f, 0.f};

    // prologue: T0{A02,B}, T0{A13}, T1{A02,B} — 10 loads, drain to 6.
    STA2(0, 0, 0); STA2(0, 2, 0); STB2(0, 0, 0); STB2(0, 1, 0);
    STA2(0, 1, 0); STA2(0, 3, 0);
    STA2(1, 0, 1); STA2(1, 2, 1); STB2(1, 0, 1); STB2(1, 1, 1);
    asm volatile("s_waitcnt vmcnt(6)" ::: "memory");
    __builtin_amdgcn_s_barrier();

    FragU fA[4][2], fB[2][2];

    for (int g = 0; g < 32; ++g) {
        const int c = g & 1, db = c ^ 1;
        const u16* sb = lds + c * G2_LDSU;

        // ---- ph1 (mh0): reads A0-3 (8) + B (4); stage A13(g+1) -> db ----
#pragma unroll
        for (int i = 0; i < 4; i++) {
            fA[i][0].u = *(const uint4*)(sb + offA[i] + cs0);
            fA[i][1].u = *(const uint4*)(sb + offA[i] + cs1);
        }
#pragma unroll
        for (int j = 0; j < 2; j++) {
            fB[j][0].u = *(const uint4*)(sb + offB[j] + cs0);
            fB[j][1].u = *(const uint4*)(sb + offB[j] + cs1);
        }
        if (g < 31) { STA2(db, 1, g + 1); STA2(db, 3, g + 1); }
        asm volatile("s_waitcnt lgkmcnt(8)" ::: "memory");
        __builtin_amdgcn_s_barrier();
        __builtin_amdgcn_s_setprio(1);
#pragma unroll
        for (int i = 0; i < 4; i++)
#pragma unroll
            for (int j = 0; j < 2; j++) {
                acc[i][j] = __builtin_amdgcn_mfma_f32_16x16x32_bf16(
                    fA[i][0].v, fB[j][0].v, acc[i][j], 0, 0, 0);
                acc[i][j] = __builtin_amdgcn_mfma_f32_16x16x32_bf16(
                    fA[i][1].v, fB[j][1].v, acc[i][j], 0, 0, 0);
            }
        __builtin_amdgcn_s_setprio(0);

        // ---- ph2 (mh1): W2 wait; reads A4-7; stage A02+B(g+2) -> cur ----
        if (g < 31) { asm volatile("s_waitcnt vmcnt(6)" ::: "memory"); }
        else        { asm volatile("s_waitcnt vmcnt(0)" ::: "memory"); }
        __builtin_amdgcn_s_barrier();
        if (g < 30) { STA2(c, 0, g + 2); STA2(c, 2, g + 2);
                      STB2(c, 0, g + 2); STB2(c, 1, g + 2); }
#pragma unroll
        for (int i = 0; i < 4; i++) {
            fA[i][0].u = *(const uint4*)(sb + offA[4 + i] + cs0);
            fA[i][1].u = *(const uint4*)(sb + offA[4 + i] + cs1);
        }
        __builtin_amdgcn_s_setprio(1);
#pragma unroll
        for (int i = 0; i < 4; i++)
#pragma unroll
            for (int j = 0; j < 2; j++) {
                acc[4 + i][j] = __builtin_amdgcn_mfma_f32_16x16x32_bf16(
                    fA[i][0].v, fB[j][0].v, acc[4 + i][j], 0, 0, 0);
                acc[4 + i][j] = __builtin_amdgcn_mfma_f32_16x16x32_bf16(
                    fA[i][1].v, fB[j][1].v, acc[4 + i][j], 0, 0, 0);
            }
        __builtin_amdgcn_s_setprio(0);

        // ---- W1: tile g+1's A-low + B resident ----
        if (g < 30)       { asm volatile("s_waitcnt vmcnt(6)" ::: "memory"); }
        else if (g == 30) { asm volatile("s_waitcnt vmcnt(2)" ::: "memory"); }
        if (g < 31) __builtin_amdgcn_s_barrier();
    }

    // epilogue: fp32 C
#pragma unroll
    for (int mi = 0; mi < 8; mi++) {
        long row0 = blockM + wm * 128 + mi * 16 + quad * 4;
#pragma unroll
        for (int nj = 0; nj < 2; nj++) {
            long col = blockN + wn * 32 + nj * 16 + l15;
#pragma unroll
            for (int r = 0; r < 4; r++)
                C[(row0 + r) * N + col] = acc[mi][nj][r];
        }
    }
#undef STA2
#undef STB2
}

// ---------------- ba as MFMA GEMM, 2-slot ring + counted vmcnt ---------------
// 64 blocks x 256 thr. M=64/block, N=32, K=2048. Raw barriers, vmcnt(3)
// (3 uniform VMEM/iter: A 16B + B 2x4B all-thread), stage k+2 after
// lgkmcnt(0)-guarded barrier. ~2-iter latency cover vs old 0-cover syncthreads.
__global__ __launch_bounds__(256) void ba_gemm(
    const u16* __restrict__ hsb, const u16* __restrict__ WbaTb,
    const float* __restrict__ A_log, const float* __restrict__ dtb,
    float* __restrict__ gout, float* __restrict__ bout) {
    __shared__ u16 As[2][64 * 32];
    __shared__ u16 Bs[2][32 * 32];
    int t = threadIdx.x;
    int lane = t & 63, w = t >> 6, l15 = lane & 15, quad = lane >> 4;
    long blockM = (long)blockIdx.x * 64;

    float4v acc[2];
    acc[0] = (float4v){0.f, 0.f, 0.f, 0.f};
    acc[1] = (float4v){0.f, 0.f, 0.f, 0.f};

    const u16* Ag  = hsb + (blockM + (t >> 2)) * (long)HID + (t & 3) * 8;
    // B 32x32 tile: 4B loads, lane l writes base+4l; wave w covers u16
    // [w*128 + l*2]; load1 = elems 0..511 (rows 0-15), load2 = rows 16-31.
    const u16* Bg1 = WbaTb + (long)(t >> 4) * HID + ((t * 2) & 31);
    const u16* Bg2 = Bg1 + 16 * (long)HID;

#define STBA(buf, k0) do {                                                     \
        GLOAD_LDS16(Ag + (k0), As[buf] + t * 8);                               \
        __builtin_amdgcn_global_load_lds(                                      \
            (const __attribute__((address_space(1))) void*)(Bg1 + (k0)),       \
            (__attribute__((address_space(3))) void*)(Bs[buf] + t * 2), 4, 0, 0); \
        __builtin_amdgcn_global_load_lds(                                      \
            (const __attribute__((address_space(1))) void*)(Bg2 + (k0)),       \
            (__attribute__((address_space(3))) void*)(Bs[buf] + 512 + t * 2), 4, 0, 0); \
    } while (0)

    STBA(0, 0);
    STBA(1, 32);

    for (int k0 = 0; k0 < HID; k0 += 32) {
        int buf = (k0 >> 5) & 1;
        if (k0 < HID - 64) { asm volatile("s_waitcnt vmcnt(3)" ::: "memory"); }
        else               { asm volatile("s_waitcnt vmcnt(0)" ::: "memory"); }
        __builtin_amdgcn_s_barrier();
        FragU fa, fb0, fb1;
        fa.u  = *(const uint4*)(As[buf] + (w * 16 + l15) * 32 + quad * 8);
        fb0.u = *(const uint4*)(Bs[buf] + l15 * 32 + quad * 8);
        fb1.u = *(const uint4*)(Bs[buf] + (16 + l15) * 32 + quad * 8);
        asm volatile("s_waitcnt lgkmcnt(0)" ::: "memory");
        __builtin_amdgcn_sched_barrier(0);
        __builtin_amdgcn_s_barrier();     // all waves' reads done before overwrite
        if (k0 + 64 < HID) STBA(buf, k0 + 64);
        acc[0] = __builtin_amdgcn_mfma_f32_16x16x32_bf16(fa.v, fb0.v, acc[0], 0, 0, 0);
        acc[1] = __builtin_amdgcn_mfma_f32_16x16x32_bf16(fa.v, fb1.v, acc[1], 0, 0, 0);
    }
#undef STBA

#pragma unroll
    for (int j = 0; j < 2; j++) {
        int n = j * 16 + l15;
#pragma unroll
        for (int r = 0; r < 4; r++) {
            long m = blockM + w * 16 + quad * 4 + r;
            int b = (int)(m >> 10), l = (int)(m & 1023);
            float v = acc[j][r];
            if (n < 16) {
                bout[((long)(b * NH + n)) * L_SEQ + l] = 1.f / (1.f + expf(-v));
            } else {
                int h = n - 16;
                float x = v + dtb[h];
                float sp = (x > 20.f) ? x : log1pf(expf(x));
                gout[((long)(b * NH + h)) * L_SEQ + l] = -expf(A_log[h]) * sp;
            }
        }
    }
}

// ---------------- conv(KS=4) + l2norm(q,k) + split v -> bf16 -----------------
__global__ __launch_bounds__(256) void conv_qkv(
    const u16* __restrict__ qkvz, const float* __restrict__ conv_w,
    const float* __restrict__ conv_b,
    u16* __restrict__ qs, u16* __restrict__ ks, u16* __restrict__ vs) {
    // XCD swizzle: consecutive bl (which share 3 of 4 qkvz rows) on same XCD.
    int orig = blockIdx.x;
    int bl = ((orig & 7) << 9) + (orig >> 3);   // 4096 = 8 x 512, bijective
    int b = bl >> 10, l = bl & 1023;
    int t = threadIdx.x;
    __shared__ float xb[CONV_DIM];
    __shared__ float red[32][9];
    __shared__ float rbuf[32];

    for (int c = t; c < CONV_DIM; c += 256) {
        float acc = conv_b[c];
        float w0 = conv_w[c * 4 + 0];
        float w1 = conv_w[c * 4 + 1];
        float w2 = conv_w[c * 4 + 2];
        float w3 = conv_w[c * 4 + 3];
        long rowbase = (long)(b * L_SEQ) * NQKVZ + c;
        if (l - 3 >= 0) acc += bf2f(qkvz[rowbase + (long)(l - 3) * NQKVZ]) * w0;
        if (l - 2 >= 0) acc += bf2f(qkvz[rowbase + (long)(l - 2) * NQKVZ]) * w1;
        if (l - 1 >= 0) acc += bf2f(qkvz[rowbase + (long)(l - 1) * NQKVZ]) * w2;
        acc += bf2f(qkvz[rowbase + (long)l * NQKVZ]) * w3;
        xb[c] = acc;
    }
    __syncthreads();
    {
        int grp = t >> 3;
        int j8 = t & 7;
        float s = 0.f;
#pragma unroll
        for (int i = 0; i < 16; i++) {
            float xv = xb[grp * 128 + j8 * 16 + i];
            s += xv * xv;
        }
        red[grp][j8] = s;
    }
    __syncthreads();
    if (t < 32) {
        float s = 0.f;
#pragma unroll
        for (int i = 0; i < 8; i++) s += red[t][i];
        rbuf[t] = rsqrtf(s + 1e-6f);
    }
    __syncthreads();
    for (int c = t; c < CONV_DIM; c += 256) {
        float xv = xb[c];
        if (c < 2048) {
            int h = c >> 7, d = c & 127;
            qs[(((long)(b * NH + h)) * L_SEQ + l) * DK + d] = f2bf(xv * rbuf[h]);
        } else if (c < 4096) {
            int c2 = c - 2048;
            int h = c2 >> 7, d = c2 & 127;
            ks[(((long)(b * NH + h)) * L_SEQ + l) * DK + d] = f2bf(xv * rbuf[16 + h]);
        } else {
            int c2 = c - 4096;
            int h = c2 >> 7, d = c2 & 127;
            vs[(((long)(b * NH + h)) * L_SEQ + l) * DV + d] = f2bf(xv);
        }
    }
}

// ---------------- gdn_prep v2: per-chunk T, P, wb, ql, kd, gam ---------------
// 1024 blocks = (bh=64) x (chunk=16); 256 threads (4 waves).
// Prefix scan via shuffle; fwd-subst = 2 parallel 32x32 (waves 0,1) +
// all-thread VALU combine T21 = -T22*A21*T11.
__global__ __launch_bounds__(256) void gdn_prep(
    const u16* __restrict__ ks_g, const u16* __restrict__ qs_g,
    const float* __restrict__ g_g, const float* __restrict__ b_g,
    u16* __restrict__ Tbuf, u16* __restrict__ Pbuf,
    u16* __restrict__ wbq, u16* __restrict__ qlq, u16* __restrict__ kdq,
    float* __restrict__ gam_g) {
    int cid = blockIdx.x;
    int bh = cid >> 4;
    int ch = cid & 15;
    long rowbase = (long)bh * L_SEQ + ch * 64;
    int t = threadIdx.x;
    int lane = t & 63, w = t >> 6, l15 = lane & 15, quad = lane >> 4;

    __shared__ u16 Kl[64 * 136];
    __shared__ u16 Ql[64 * 136];
    __shared__ float Am[64 * 66];
    __shared__ float Tm[64 * 66];
    __shared__ float Tt[32 * 33];
    __shared__ float Gs[64], lamL[64], betaL[64], dlL[64];

    {   // stage K,Q rows bf16 -> padded LDS; stage g, beta
        int row = t >> 2, seg = (t & 3) * 32;
        const u16* ksrc = ks_g + (rowbase + row) * DK + seg;
        const u16* qsrc = qs_g + (rowbase + row) * DK + seg;
        *(uint4*)&Kl[row * 136 + seg]      = *(const uint4*)ksrc;
        *(uint4*)&Kl[row * 136 + seg + 8]  = *(const uint4*)(ksrc + 8);
        *(uint4*)&Kl[row * 136 + seg + 16] = *(const uint4*)(ksrc + 16);
        *(uint4*)&Kl[row * 136 + seg + 24] = *(const uint4*)(ksrc + 24);
        *(uint4*)&Ql[row * 136 + seg]      = *(const uint4*)qsrc;
        *(uint4*)&Ql[row * 136 + seg + 8]  = *(const uint4*)(qsrc + 8);
        *(uint4*)&Ql[row * 136 + seg + 16] = *(const uint4*)(qsrc + 16);
        *(uint4*)&Ql[row * 136 + seg + 24] = *(const uint4*)(qsrc + 24);
        if (t < 64) Gs[t] = g_g[rowbase + t];
        else if (t < 128) betaL[t - 64] = b_g[rowbase + t - 64];
    }
    __syncthreads();
    if (t < 64) {   // inclusive prefix scan (Kogge-Stone, wave 0)
        float gv = Gs[t];
#pragma unroll
        for (int off = 1; off < 64; off <<= 1) {
            float n = __shfl_up(gv, off);
            if (lane >= off) gv += n;
        }
        Gs[t] = gv;
    }
    __syncthreads();
    if (t < 64) {
        float G63 = Gs[63];
        float lm = expf(Gs[t]);
        lamL[t] = lm;
        dlL[t] = expf(G63 - Gs[t]);
        if (t == 0) gam_g[cid] = expf(G63);
    }
    // MFMA: KK^T and QK^T (wave w = row-stripe w*16)
    float4v accKK[4], accQK[4];
#pragma unroll
    for (int tj = 0; tj < 4; tj++) {
        accKK[tj] = (float4v){0.f, 0.f, 0.f, 0.f};
        accQK[tj] = (float4v){0.f, 0.f, 0.f, 0.f};
    }
#pragma unroll
    for (int k0 = 0; k0 < 128; k0 += 32) {
        FragU ka, qa;
        ka.u = *(const uint4*)&Kl[(w * 16 + l15) * 136 + k0 + quad * 8];
        qa.u = *(const uint4*)&Ql[(w * 16 + l15) * 136 + k0 + quad * 8];
#pragma unroll
        for (int tj = 0; tj < 4; tj++) {
            FragU kb;
            kb.u = *(const uint4*)&Kl[(tj * 16 + l15) * 136 + k0 + quad * 8];
            accKK[tj] = __builtin_amdgcn_mfma_f32_16x16x32_bf16(ka.v, kb.v, accKK[tj], 0, 0, 0);
            accQK[tj] = __builtin_amdgcn_mfma_f32_16x16x32_bf16(qa.v, kb.v, accQK[tj], 0, 0, 0);
        }
    }
    __syncthreads();   // lamL/betaL/dlL visible
    // mask + scale; Am -> LDS fp32, P -> global bf16
#pragma unroll
    for (int tj = 0; tj < 4; tj++) {
#pragma unroll
        for (int r = 0; r < 4; r++) {
            int ti_ = w * 16 + quad * 4 + r;
            int j = tj * 16 + l15;
            float e = (j <= ti_) ? expf(Gs[ti_] - Gs[j]) : 0.f;
            Am[ti_ * 66 + j] = (j < ti_) ? betaL[ti_] * e * accKK[tj][r] : 0.f;
            Pbuf[(long)cid * 4096 + ti_ * 64 + j] =
                (j <= ti_) ? f2bf(GDN_SCALE * e * accQK[tj][r]) : (u16)0;
        }
    }
    // wbq, qlq (row-major [64][128])
    {
        int row = t >> 2, seg = (t & 3) * 32;
        float sw = -betaL[row] * lamL[row];
        float sq = GDN_SCALE * lamL[row];
#pragma unroll
        for (int c0 = 0; c0 < 32; c0 += 8) {
            u16 wt[8], qt2[8];
#pragma unroll
            for (int j2 = 0; j2 < 8; j2++) {
                wt[j2]  = f2bf(sw * bf2f(Kl[row * 136 + seg + c0 + j2]));
                qt2[j2] = f2bf(sq * bf2f(Ql[row * 136 + seg + c0 + j2]));
            }
            *(uint4*)&wbq[(long)cid * 8192 + row * 128 + seg + c0] = *(uint4*)wt;
            *(uint4*)&qlq[(long)cid * 8192 + row * 128 + seg + c0] = *(uint4*)qt2;
        }
    }
    // kdq (transposed [128 k][64 t]) — all 256 threads
    {
        int k = t & 127, t0b = (t >> 7) * 32;
#pragma unroll
        for (int t0 = 0; t0 < 32; t0 += 8) {
            u16 tmp[8];
#pragma unroll
            for (int j2 = 0; j2 < 8; j2++)
                tmp[j2] = f2bf(dlL[t0b + t0 + j2] * bf2f(Kl[(t0b + t0 + j2) * 136 + k]));
            *(uint4*)&kdq[(long)cid * 8192 + k * 64 + t0b + t0] = *(uint4*)tmp;
        }
    }
    __syncthreads();
    // fwd-subst: T11 (lanes 0-31 of wave 0), T22 (lanes 0-31 of wave 1), zero T12
    if (t < 32) {
        int c = t;
        for (int i = 0; i < 32; i++) {
            float s = (i == c) ? 1.f : 0.f;
            for (int j = 0; j < i; j++) s -= Am[i * 66 + j] * Tm[j * 66 + c];
            Tm[i * 66 + c] = s;
        }
    } else if (t >= 64 && t < 96) {
        int c = 32 + (t - 64);
        for (int i = 32; i < 64; i++) {
            float s = (i == c) ? 1.f : 0.f;
            for (int j = 32; j < i; j++) s -= Am[i * 66 + j] * Tm[j * 66 + c];
            Tm[i * 66 + c] = s;
        }
    } else if (t >= 128 && t < 192) {
        int idx = t - 128;
        for (int kk = 0; kk < 16; kk++) {
            int e = idx * 16 + kk;
            Tm[(e >> 5) * 66 + 32 + (e & 31)] = 0.f;
        }
    }
    __syncthreads();
    {   // Tt = A21 * T11  (32x32, 4 elems/thread)
        int e0 = t * 4;
#pragma unroll
        for (int kk = 0; kk < 4; kk++) {
            int e = e0 + kk; int i = e >> 5, c = e & 31;
            float s = 0.f;
            for (int j = 0; j < 32; j++) s += Am[(32 + i) * 66 + j] * Tm[j * 66 + c];
            Tt[i * 33 + c] = s;
        }
    }
    __syncthreads();
    {   // T21 = -T22 * Tt
        int e0 = t * 4;
#pragma unroll
        for (int kk = 0; kk < 4; kk++) {
            int e = e0 + kk; int i = e >> 5, c = e & 31;
            float s = 0.f;
            for (int j = 0; j < 32; j++) s -= Tm[(32 + i) * 66 + 32 + j] * Tt[j * 33 + c];
            Tm[(32 + i) * 66 + c] = s;
        }
    }
    __syncthreads();
    {   // T -> global bf16
        int row = t >> 2, c0 = (t & 3) * 16;
        u16 tmp[16];
#pragma unroll
        for (int i = 0; i < 16; i++) tmp[i] = f2bf(Tm[row * 66 + c0 + i]);
        *(uint4*)&Tbuf[(long)cid * 4096 + row * 64 + c0]     = *(uint4*)tmp;
        *(uint4*)&Tbuf[(long)cid * 4096 + row * 64 + c0 + 8] = *(uint4*)(tmp + 8);
    }
}

// ---------------- gdn_chunk v3: direct-global fragments, 512 blocks ----------
// 512 blocks = (bh=64) x (dc=8: 16 v-cols). 256 threads (4 waves).
// XCD swizzle: the 8 dc-blocks of one bh (which read the SAME 1 MB of
// T/P/wb/ql/kd) land on the same XCD -> per-XCD L2 reuse instead of 8x fetch.
__global__ __launch_bounds__(256) void gdn_chunk(
    const u16* __restrict__ vs_g, const float* __restrict__ b_g,
    const u16* __restrict__ Tq, const u16* __restrict__ Pq,
    const u16* __restrict__ wbq, const u16* __restrict__ qlq,
    const u16* __restrict__ kdq, const float* __restrict__ gam_g,
    float* __restrict__ o_g) {
    int orig = blockIdx.x;
    int bid = ((orig & 7) << 6) + (orig >> 3);   // 512 = 8 x 64, bijective
    int dc = bid & 7;
    int bh = bid >> 3;
    int b = bh >> 4, h = bh & 15;
    int t = threadIdx.x;
    int lane = t & 63, w = t >> 6, l15 = lane & 15, quad = lane >> 4;

    __shared__ u16 s0h[16 * 136], s0l[16 * 136];   // S0^T [v][k] hi/lo
    __shared__ float vO[64 * 20];                  // vb / O, [t][v]
    __shared__ u16 rhsT[16 * 72], DT[16 * 72];     // [v][t]

    float4v S0r[2];
    S0r[0] = (float4v){0.f, 0.f, 0.f, 0.f};
    S0r[1] = (float4v){0.f, 0.f, 0.f, 0.f};

    const int orow = t >> 2, oseg = (t & 3) * 4;   // 64 rows x 16 cols

    for (int ch = 0; ch < 16; ch++) {
        int cid = bh * 16 + ch;
        long rowbase = (long)bh * L_SEQ + ch * 64;
        float gam = gam_g[cid];

        // prefetch wb fragments (used phase b)
        const u16* wbp = wbq + (long)cid * 8192 + (w * 16 + l15) * 128 + quad * 8;
        uint4 wbf0 = *(const uint4*)(wbp);
        uint4 wbf1 = *(const uint4*)(wbp + 32);
        uint4 wbf2 = *(const uint4*)(wbp + 64);
        uint4 wbf3 = *(const uint4*)(wbp + 96);

        // ---- phase a: store prev O, load vb, split S0 ----
        if (ch > 0) {
            float4 a = *(const float4*)&vO[orow * 20 + oseg];
            float* d2 = o_g + (((long)b * L_SEQ + (ch - 1) * 64 + orow) * 16 + h) * 128L
                        + dc * 16 + oseg;
            *(float4*)d2 = a;
        }
        {
            float beta = b_g[rowbase + orow];
            uint2 vv = *(const uint2*)(vs_g + (rowbase + orow) * DV + dc * 16 + oseg);
            const u16* vp = (const u16*)&vv;
#pragma unroll
            for (int j2 = 0; j2 < 4; j2++)
                vO[orow * 20 + oseg + j2] = beta * bf2f(vp[j2]);
        }
#pragma unroll
        for (int ktl = 0; ktl < 2; ktl++) {
            int kc = (2 * w + ktl) * 16 + l15;
#pragma unroll
            for (int r = 0; r < 4; r++) {
                float x = S0r[ktl][r];
                u16 hi = f2bf(x);
                float lo = x - bf2f(hi);
                s0h[(quad * 4 + r) * 136 + kc] = hi;
                s0l[(quad * 4 + r) * 136 + kc] = f2bf(lo);
            }
        }
        __syncthreads();

        // ---- phase b: RHS[t][v] = vb + wb*(S0h+S0l) -> rhsT ----
        const u16* Tp = Tq + (long)cid * 4096 + (w * 16 + l15) * 64 + quad * 8;
        uint4 Tf0 = *(const uint4*)(Tp);        // prefetch for phase c
        uint4 Tf1 = *(const uint4*)(Tp + 32);
        {
            float4v acc;
#pragma unroll
            for (int r = 0; r < 4; r++)
                acc[r] = vO[(w * 16 + quad * 4 + r) * 20 + l15];
            uint4 wbf[4] = {wbf0, wbf1, wbf2, wbf3};
#pragma unroll
            for (int k0 = 0; k0 < 4; k0++) {
                FragU a, bh_, bl_;
                a.u = wbf[k0];
                bh_.u = *(const uint4*)&s0h[l15 * 136 + k0 * 32 + quad * 8];
                acc = __builtin_amdgcn_mfma_f32_16x16x32_bf16(a.v, bh_.v, acc, 0, 0, 0);
                bl_.u = *(const uint4*)&s0l[l15 * 136 + k0 * 32 + quad * 8];
                acc = __builtin_amdgcn_mfma_f32_16x16x32_bf16(a.v, bl_.v, acc, 0, 0, 0);
            }
            u16 tmp[4] = {f2bf(acc[0]), f2bf(acc[1]), f2bf(acc[2]), f2bf(acc[3])};
            *(uint2*)&rhsT[l15 * 72 + w * 16 + quad * 4] = *(uint2*)tmp;
        }
        __syncthreads();

        // ---- phase c: D = T*RHS -> DT ----
        const u16* qlp = qlq + (long)cid * 8192 + (w * 16 + l15) * 128 + quad * 8;
        uint4 qlf0 = *(const uint4*)(qlp);      // prefetch for phase d
        uint4 qlf1 = *(const uint4*)(qlp + 32);
        uint4 qlf2 = *(const uint4*)(qlp + 64);
        uint4 qlf3 = *(const uint4*)(qlp + 96);
        const u16* Pp = Pq + (long)cid * 4096 + (w * 16 + l15) * 64 + quad * 8;
        uint4 Pf0 = *(const uint4*)(Pp);
        uint4 Pf1 = *(const uint4*)(Pp + 32);
        {
            float4v acc = (float4v){0.f, 0.f, 0.f, 0.f};
            uint4 Tf[2] = {Tf0, Tf1};
#pragma unroll
            for (int k0 = 0; k0 < 2; k0++) {
                FragU a, b_;
                a.u = Tf[k0];
                b_.u = *(const uint4*)&rhsT[l15 * 72 + k0 * 32 + quad * 8];
                acc = __builtin_amdgcn_mfma_f32_16x16x32_bf16(a.v, b_.v, acc, 0, 0, 0);
            }
            u16 tmp[4] = {f2bf(acc[0]), f2bf(acc[1]), f2bf(acc[2]), f2bf(acc[3])};
            *(uint2*)&DT[l15 * 72 + w * 16 + quad * 4] = *(uint2*)tmp;
        }
        __syncthreads();

        // ---- phase d: O = ql*S0 + P*D ; S0 = gam*S0 + kd^T D ----
        uint4 kdf[2][2];
#pragma unroll
        for (int ktl = 0; ktl < 2; ktl++) {
            const u16* kdp = kdq + (long)cid * 8192 + ((2 * w + ktl) * 16 + l15) * 64 + quad * 8;
            kdf[ktl][0] = *(const uint4*)(kdp);
            kdf[ktl][1] = *(const uint4*)(kdp + 32);
        }
        {
            float4v acc = (float4v){0.f, 0.f, 0.f, 0.f};
            uint4 qlf[4] = {qlf0, qlf1, qlf2, qlf3};
#pragma unroll
            for (int k0 = 0; k0 < 4; k0++) {
                FragU a, bh_, bl_;
                a.u = qlf[k0];
                bh_.u = *(const uint4*)&s0h[l15 * 136 + k0 * 32 + quad * 8];
                acc = __builtin_amdgcn_mfma_f32_16x16x32_bf16(a.v, bh_.v, acc, 0, 0, 0);
                bl_.u = *(const uint4*)&s0l[l15 * 136 + k0 * 32 + quad * 8];
                acc = __builtin_amdgcn_mfma_f32_16x16x32_bf16(a.v, bl_.v, acc, 0, 0, 0);
            }
            uint4 Pf[2] = {Pf0, Pf1};
#pragma unroll
            for (int k0 = 0; k0 < 2; k0++) {
                FragU a, b_;
                a.u = Pf[k0];
                b_.u = *(const uint4*)&DT[l15 * 72 + k0 * 32 + quad * 8];
                acc = __builtin_amdgcn_mfma_f32_16x16x32_bf16(a.v, b_.v, acc, 0, 0, 0);
            }
#pragma unroll
            for (int r = 0; r < 4; r++)
                vO[(w * 16 + quad * 4 + r) * 20 + l15] = acc[r];
        }
#pragma unroll
        for (int ktl = 0; ktl < 2; ktl++) {
            float4v acc = S0r[ktl];
#pragma unroll
            for (int r = 0; r < 4; r++) acc[r] *= gam;
#pragma unroll
            for (int t0 = 0; t0 < 2; t0++) {
                FragU a, b_;
                a.u = *(const uint4*)&DT[l15 * 72 + t0 * 32 + quad * 8];
                b_.u = kdf[ktl][t0];
                acc = __builtin_amdgcn_mfma_f32_16x16x32_bf16(a.v, b_.v, acc, 0, 0, 0);
            }
            S0r[ktl] = acc;
        }
        __syncthreads();
    }
    // final chunk's O store
    {
        float4 a = *(const float4*)&vO[orow * 20 + oseg];
        float* d2 = o_g + (((long)b * L_SEQ + 15 * 64 + orow) * 16 + h) * 128L
                    + dc * 16 + oseg;
        *(float4*)d2 = a;
    }
}

// ---------------- gated RMS norm -> bf16 A2 ----------------------------------
__global__ __launch_bounds__(128) void gated_norm(
    const float* __restrict__ o, const u16* __restrict__ qkvz,
    const float* __restrict__ norm_w, u16* __restrict__ A2) {
    int bid = blockIdx.x;  // (b*L+l)*16 + h
    int t = threadIdx.x;   // 0..127
    float ov = o[(long)bid * 128 + t];
    float s = ov * ov;
#pragma unroll
    for (int off = 32; off > 0; off >>= 1) s += __shfl_down(s, off);
    __shared__ float ws2[2];
    if ((t & 63) == 0) ws2[t >> 6] = s;
    __syncthreads();
    float tot = ws2[0] + ws2[1];
    float rinv = rsqrtf(tot * (1.f / 128.f) + 1e-6f);
    int bl = bid >> 4, h = bid & 15;
    float z = bf2f(qkvz[(long)bl * NQKVZ + CONV_DIM + h * 128 + t]);
    float sig = 1.f / (1.f + expf(-z));
    float val = ov * rinv * norm_w[t] * sig;
    A2[(long)bl * 2048 + h * 128 + t] = f2bf(val);
}

// ---------------- host-side launcher -----------------------------------------
extern "C" void kernel_launch(void* const* d_in, const int* in_sizes, int n_in,
                              void* d_out, int out_size, void* d_ws, size_t ws_size,
                              hipStream_t stream) {
    const float* hs    = (const float*)d_in[0];
    const float* Wqkvz = (const float*)d_in[1];
    const float* Wba   = (const float*)d_in[2];
    const float* convw = (const float*)d_in[3];
    const float* convb = (const float*)d_in[4];
    const float* A_log = (const float*)d_in[5];
    const float* dtb   = (const float*)d_in[6];
    const float* normw = (const float*)d_in[7];
    const float* Wout  = (const float*)d_in[8];

    char* ws = (char*)d_ws;
    size_t off = 0;
    auto alloc = [&](size_t bytes) {
        size_t o = off;
        off = (off + bytes + 255) & ~(size_t)255;
        return o;
    };
    // region0: WqkvzT (bf16) — dead after GEMM1, reused for os (fp32)
    size_t r0 = alloc((size_t)NQKVZ * HID * 2);
    // region1: hs_bf16 — kept through ba_gemm; A2 aliases after
    size_t r1 = alloc((size_t)4096 * HID * 2);
    u16*   WqkvzT = (u16*)(ws + r0);
    float* os     = (float*)(ws + r0);
    u16*   hsb    = (u16*)(ws + r1);
    u16*   A2     = (u16*)(ws + r1);   // written by gated_norm after ba_gemm done
    u16*   qkvz   = (u16*)(ws + alloc((size_t)4096 * NQKVZ * 2));
    u16*   qs     = (u16*)(ws + alloc((size_t)64 * L_SEQ * DK * 2));
    u16*   ks     = (u16*)(ws + alloc((size_t)64 * L_SEQ * DK * 2));
    u16*   vs     = (u16*)(ws + alloc((size_t)64 * L_SEQ * DV * 2));
    float* gs     = (float*)(ws + alloc((size_t)64 * L_SEQ * 4));
    float* bs     = (float*)(ws + alloc((size_t)64 * L_SEQ * 4));
    u16*   WoutT  = (u16*)(ws + alloc((size_t)HID * 2048 * 2));
    u16*   WbaTb  = (u16*)(ws + alloc((size_t)32 * HID * 2));
    u16*   Tbuf   = (u16*)(ws + alloc((size_t)1024 * 4096 * 2));
    u16*   Pbuf   = (u16*)(ws + alloc((size_t)1024 * 4096 * 2));
    u16*   wbq    = (u16*)(ws + alloc((size_t)1024 * 8192 * 2));
    u16*   qlq    = (u16*)(ws + alloc((size_t)1024 * 8192 * 2));
    u16*   kdq    = (u16*)(ws + alloc((size_t)1024 * 8192 * 2));
    float* gamb   = (float*)(ws + alloc((size_t)1024 * 4));

    // 1. convert + transposes
    hipLaunchKernelGGL(f32_to_bf16, dim3(4096), dim3(256), 0, stream, hs, hsb);
    hipLaunchKernelGGL(transpose_f32_bf16, dim3(NQKVZ / 32, HID / 32), dim3(256), 0, stream,
                       Wqkvz, WqkvzT, HID, NQKVZ);
    hipLaunchKernelGGL(transpose_f32_bf16, dim3(2048 / 32, 2048 / 32), dim3(256), 0, stream,
                       Wout, WoutT, 2048, 2048);
    hipLaunchKernelGGL(transpose_f32_bf16, dim3(1, HID / 32), dim3(256), 0, stream,
                       Wba, WbaTb, HID, 32);

    // 2. GEMM1: qkvz = hs @ W_qkvz (r2 schedule, measured-best)
    hipLaunchKernelGGL(gemm1_8ph, dim3(512), dim3(512), 0, stream,
                       hsb, WqkvzT, qkvz);

    // 3. ba (MFMA, 2-slot ring) -> g, beta
    hipLaunchKernelGGL(ba_gemm, dim3(64), dim3(256), 0, stream,
                       hsb, WbaTb, A_log, dtb, gs, bs);

    // 4. conv + l2norm -> q,k,v (bf16), XCD-swizzled
    hipLaunchKernelGGL(conv_qkv, dim3(4096), dim3(256), 0, stream,
                       qkvz, convw, convb, qs, ks, vs);

    // 5a. chunk prep (parallel): T, P, wb, ql, kd, gam
    hipLaunchKernelGGL(gdn_prep, dim3(1024), dim3(256), 0, stream,
                       ks, qs, gs, bs, Tbuf, Pbuf, wbq, qlq, kdq, gamb);

    // 5b. chunk recurrence (MFMA, direct-global fragments, XCD-swizzled)
    hipLaunchKernelGGL(gdn_chunk, dim3(512), dim3(256), 0, stream,
                       vs, bs, Tbuf, Pbuf, wbq, qlq, kdq, gamb, os);

    // 6. gated RMS norm -> bf16 A2
    hipLaunchKernelGGL(gated_norm, dim3(4096 * NH), dim3(128), 0, stream,
                       os, qkvz, normw, A2);

    // 7. GEMM2: out = A2 @ W_out (256x128 2-phase counted-vmcnt)
    hipLaunchKernelGGL(gemm2_2ph, dim3(256), dim3(512), 0, stream,
                       A2, WoutT, (float*)d_out);
}